// Round 8
// baseline (116.203 us; speedup 1.0000x reference)
//
#include <hip/hip_runtime.h>
#include <hip/hip_bf16.h>

// B=16, C=64, CQ=8, H=W=128
typedef unsigned short u16;
typedef __attribute__((ext_vector_type(8))) short    bf16x8;
typedef __attribute__((ext_vector_type(8))) unsigned short us8;
typedef __attribute__((ext_vector_type(4))) unsigned short us4;
typedef __attribute__((ext_vector_type(4))) float    f32x4;
typedef __attribute__((ext_vector_type(2))) unsigned int u32x2;

__device__ __forceinline__ u16 f2bf(float f) {
    unsigned u = __float_as_uint(f);
    return (u16)((u + 0x7FFFu + ((u >> 16) & 1u)) >> 16);
}
__device__ __forceinline__ float bf2f(u16 v) {
    return __uint_as_float((unsigned)v << 16);
}

// ---------------------------------------------------------------------------
// Kernel 0: W prep. Packs Wv/Wq/Wk into bf16 B-frag slots
// Wpk[nt(5)][kt(2)][lane(64)][8]; biasf[80] = {bv, bq, bk}.
// ---------------------------------------------------------------------------
__global__ __launch_bounds__(256) void wprep_kernel(
    const float* __restrict__ Wq, const float* __restrict__ bq,
    const float* __restrict__ Wk, const float* __restrict__ bk,
    const float* __restrict__ Wv, const float* __restrict__ bv,
    u16* __restrict__ Wpk, float* __restrict__ biasf)
{
    int t = threadIdx.x;
    for (int s = t; s < 640; s += 256) {
        int nt = s >> 7;
        int kt = (s >> 6) & 1;
        int l  = s & 63;
        int n  = (nt << 4) | (l & 15);
        int k0 = kt * 32 + ((l >> 4) << 3);
        const float* row;
        if (n < 64) row = Wv + n * 64;
        else if (n < 72) row = Wq + (n - 64) * 64;
        else row = Wk + (n - 72) * 64;
        us8 o;
#pragma unroll
        for (int j = 0; j < 8; j++) o[j] = f2bf(row[k0 + j]);
        *(us8*)&Wpk[s * 8] = o;
    }
    if (t < 80) {
        float bb;
        if (t < 64) bb = bv[t];
        else if (t < 72) bb = bq[t - 64];
        else bb = bk[t - 72];
        biasf[t] = bb;
    }
}

// ---------------------------------------------------------------------------
// Kernel 1: projections via MFMA. Block = 256 pixels, 512 thr = 8 waves.
// ---------------------------------------------------------------------------
#define PH 258   // LDS x-tile row stride (u16); ==2 mod 4 -> conflict-free frags
__global__ __launch_bounds__(512) void proj_kernel(
    const float* __restrict__ x, const u16* __restrict__ Wpk,
    const float* __restrict__ biasf,
    u16* __restrict__ vb16, u16* __restrict__ qkTr)
{
    __shared__ u16 Xh[64 * PH];   // 33 KB

    int t = threadIdx.x;
    int bid = blockIdx.x;
    int wg = ((bid & 7) << 7) | (bid >> 3);   // b-matched XCD swizzle
    int b = wg >> 6;
    int hw0 = (wg & 63) << 8;
    const float* xb = x + ((long)b << 20) + hw0;

#pragma unroll
    for (int it = 0; it < 8; it++) {
        int c = it * 8 + (t >> 6);
        int pix = (t & 63) << 2;
        float4 xv = *(const float4*)&xb[(c << 14) + pix];
        unsigned lo = ((unsigned)f2bf(xv.y) << 16) | f2bf(xv.x);
        unsigned hi = ((unsigned)f2bf(xv.w) << 16) | f2bf(xv.z);
        unsigned* dst = (unsigned*)&Xh[c * PH + pix];
        dst[0] = lo; dst[1] = hi;
    }
    __syncthreads();

    int wv = t >> 6, l = t & 63;
    int m16 = l & 15, kg = l >> 4;
    int pixb = wv << 5;

    bf16x8 af[2][2];
#pragma unroll
    for (int mt = 0; mt < 2; mt++) {
        int pix = pixb + (mt << 4) + m16;
#pragma unroll
        for (int kt = 0; kt < 2; kt++) {
            us8 a;
#pragma unroll
            for (int j = 0; j < 8; j++)
                a[j] = Xh[(kt * 32 + (kg << 3) + j) * PH + pix];
            af[mt][kt] = (bf16x8)a;
        }
    }

    f32x4 acc[2][5];
#pragma unroll
    for (int nt = 0; nt < 5; nt++) {
        float bb = biasf[(nt << 4) + m16];
        f32x4 binit = {bb, bb, bb, bb};
        bf16x8 b0 = *(const bf16x8*)&Wpk[(((nt << 1) + 0) << 9) + (l << 3)];
        bf16x8 b1 = *(const bf16x8*)&Wpk[(((nt << 1) + 1) << 9) + (l << 3)];
#pragma unroll
        for (int mt = 0; mt < 2; mt++) {
            f32x4 a_ = binit;
            a_ = __builtin_amdgcn_mfma_f32_16x16x32_bf16(af[mt][0], b0, a_, 0, 0, 0);
            a_ = __builtin_amdgcn_mfma_f32_16x16x32_bf16(af[mt][1], b1, a_, 0, 0, 0);
            acc[mt][nt] = a_;
        }
    }

    long vbase = ((long)b << 20) + hw0;
#pragma unroll
    for (int mt = 0; mt < 2; mt++) {
        int pix0 = pixb + (mt << 4) + (kg << 2);
#pragma unroll
        for (int nt = 0; nt < 4; nt++) {
            int c = (nt << 4) + m16;
            us4 pkd = { f2bf(acc[mt][nt][0]), f2bf(acc[mt][nt][1]),
                        f2bf(acc[mt][nt][2]), f2bf(acc[mt][nt][3]) };
            *(us4*)&vb16[vbase + (c << 14) + pix0] = pkd;
        }
#pragma unroll
        for (int r = 0; r < 4; r++)
            qkTr[((((long)(b << 14)) + hw0 + pix0 + r) << 4) + m16] = f2bf(acc[mt][4][r]);
    }
}

// ---------------------------------------------------------------------------
// Kernel 2: v transpose: vb16[b][c][g][w] -> vTc[b][w][c][g] (bf16).
// ---------------------------------------------------------------------------
__global__ __launch_bounds__(256) void vtrans_kernel(
    const u16* __restrict__ vb16, u16* __restrict__ vTc)
{
    __shared__ u16 tile[32][33];
    int t = threadIdx.x;
    int bid = blockIdx.x;
    int vwg = ((bid & 7) << 11) | (bid >> 3);  // b-matched XCD swizzle
    int b = vwg >> 10;
    int c = (vwg >> 4) & 63;
    int g0 = ((vwg >> 2) & 3) * 32, w0 = (vwg & 3) * 32;
    const u16* src = vb16 + ((b * 64 + c) << 14);
#pragma unroll
    for (int it = 0; it < 4; it++) {
        int i = it * 8 + (t >> 5), j = t & 31;
        tile[i][j] = src[(g0 + i) * 128 + w0 + j];
    }
    __syncthreads();
    int j = t >> 3, i4 = (t & 7) * 4;
    us4 o = { tile[i4][j], tile[i4 + 1][j], tile[i4 + 2][j], tile[i4 + 3][j] };
    *(us4*)&vTc[((b * 128 + w0 + j) * 64 + c) * 128 + g0 + i4] = o;
}

// ---------------------------------------------------------------------------
// Kernel 3: column attention, c-split. Block (b, w, ch), 4096 blocks.
// QK^T full (duplicated per half) -> Epk; PV on 32-c half: D[c][h].
// Writes accHt[b][w][h][c] bf16 + sH (ch==0 only).
// ---------------------------------------------------------------------------
__global__ __launch_bounds__(512) void colH_kernel(
    const u16* __restrict__ qkTr, const u16* __restrict__ vTc,
    u16* __restrict__ accHt, float* __restrict__ sH)
{
    __shared__ u16 Qpk[129 * 8];
    __shared__ u16 Kpk[129 * 8];
    __shared__ u16 Epk[2048 * 8];      // 32 KB
    __shared__ u16 Vs[512 * 8];        // 8 KB (32 c)

    int t = threadIdx.x;
    int bid = blockIdx.x;
    int wg = ((bid & 7) << 9) | (bid >> 3);   // bijective, b-contiguous per XCD
    int b = wg >> 8, w = (wg >> 1) & 127, ch = wg & 1;

    if (t < 128) {
        const u16* p = qkTr + (((long)((b << 14) + t * 128 + w)) << 4);
        *(us8*)&Qpk[t * 8] = *(const us8*)p;
        *(us8*)&Kpk[t * 8] = *(const us8*)(p + 8);
    } else if (t == 128) {
        us8 z = {0,0,0,0,0,0,0,0};
        *(us8*)&Qpk[128 * 8] = z;
        *(us8*)&Kpk[128 * 8] = z;
    }

    // stage V^T half-tile (32 c x 128 g), XOR-swizzled source chunks
    const u16* vB = vTc + (((long)(b * 128 + w)) << 13) + (ch << 12);
    {
        int c = t >> 4, s = t & 15;
        int src = (c << 4) | (s & 8) | ((s ^ c) & 7);
        *(us8*)&Vs[t << 3] = *(const us8*)&vB[src << 3];
    }
    __syncthreads();

    int wv = t >> 6, l = t & 63;
    int m16 = l & 15, kg = l >> 4;
    f32x4 zero4 = {0.f, 0.f, 0.f, 0.f};

    // ---- QK^T (full E, diag mask) ----
    int gt = wv;
    bf16x8 afr;
    { int sl = (kg == 0) ? (gt * 16 + m16) : 128;
      afr = *(const bf16x8*)&Kpk[sl * 8]; }
    int kgr = ((gt & 1) << 1) | (kg >> 1);
    int jb  = (kg & 1) << 2;
    int gbase = gt * 16 + kg * 4;
#pragma unroll
    for (int ht = 0; ht < 8; ht++) {
        int slB = (kg == 0) ? (ht * 16 + m16) : 128;
        bf16x8 bfr = *(const bf16x8*)&Qpk[slB * 8];
        f32x4 e = __builtin_amdgcn_mfma_f32_16x16x32_bf16(afr, bfr, zero4, 0, 0, 0);
        u16 u0[4];
#pragma unroll
        for (int r = 0; r < 4; r++) {
            int g = gbase + r, h = ht * 16 + m16;
            float val = (g == h) ? 0.f : __expf(e[r]);
            u0[r] = f2bf(val);
        }
        int eidx = ((((ht << 2) | (gt >> 1)) * 64 + kgr * 16 + m16) << 3) + jb;
        u32x2 pk2;
        pk2.x = (unsigned)u0[0] | ((unsigned)u0[1] << 16);
        pk2.y = (unsigned)u0[2] | ((unsigned)u0[3] << 16);
        *(u32x2*)&Epk[eidx] = pk2;
    }
    __syncthreads();

    // ---- PV half: D[c(32)][h], wave owns h-tile mt=wv ----
    int mt = wv;
    bf16x8 bE[4];
#pragma unroll
    for (int kt = 0; kt < 4; kt++)
        bE[kt] = *(const bf16x8*)&Epk[(((mt << 2) + kt) * 64 + l) << 3];

    bf16x8 ones;
    short ov = (m16 == 0) ? (short)0x3F80 : (short)0;
#pragma unroll
    for (int j = 0; j < 8; j++) ones[j] = ov;

    f32x4 acc[3];
#pragma unroll
    for (int i = 0; i < 3; i++) acc[i] = zero4;

#pragma unroll
    for (int ct = 0; ct < 2; ct++) {
#pragma unroll
        for (int kt = 0; kt < 4; kt++) {
            int slot = ((ct * 16 + m16) << 4) | ((((kt << 2) | kg)) ^ (m16 & 7));
            bf16x8 aV = *(const bf16x8*)&Vs[slot << 3];
            acc[ct] = __builtin_amdgcn_mfma_f32_16x16x32_bf16(aV, bE[kt], acc[ct], 0, 0, 0);
        }
    }
    if (ch == 0) {
#pragma unroll
        for (int kt = 0; kt < 4; kt++)
            acc[2] = __builtin_amdgcn_mfma_f32_16x16x32_bf16(ones, bE[kt], acc[2], 0, 0, 0);
    }

    long obase = (((long)(b * 128 + w)) * 128 + mt * 16 + m16) * 64 + (ch << 5);
#pragma unroll
    for (int ct = 0; ct < 2; ct++) {
        us4 pkd = { f2bf(acc[ct][0]), f2bf(acc[ct][1]), f2bf(acc[ct][2]), f2bf(acc[ct][3]) };
        *(us4*)&accHt[obase + ct * 16 + kg * 4] = pkd;
    }
    if (ch == 0 && kg == 0)
        sH[(b * 128 + w) * 128 + mt * 16 + m16] = acc[2][0];
}

// ---------------------------------------------------------------------------
// Kernel 4: row attention + fused finalize, c-split. Block (b, h, ch).
// ---------------------------------------------------------------------------
__global__ __launch_bounds__(512) void rowW_fin_kernel(
    const u16* __restrict__ qkTr, const u16* __restrict__ vb16,
    const u16* __restrict__ accHt, const float* __restrict__ sH,
    const float* __restrict__ x, const float* __restrict__ gamma,
    float* __restrict__ out)
{
    __shared__ u16 Qpk[129 * 8];
    __shared__ u16 Kpk[129 * 8];
    __shared__ union FU {
        struct { u16 Epk[2048 * 8]; u16 Vs[512 * 8]; } s;   // 40 KB
        struct { float outS[32 * 132]; } f;                  // 16.5 KB
    } uu;

    int t = threadIdx.x;
    int bid = blockIdx.x;
    int wg = ((bid & 7) << 9) | (bid >> 3);
    int b = wg >> 8, h = (wg >> 1) & 127, ch = wg & 1;
    float gm = gamma[0];

    int wv = t >> 6, l = t & 63;
    int m16 = l & 15, kg = l >> 4;
    int wcol = wv * 16 + m16;

    // ---- staging ----
    if (t < 128) {
        const u16* p = qkTr + (((long)((b << 14) + h * 128 + t)) << 4);
        *(us8*)&Qpk[t * 8] = *(const us8*)p;
        *(us8*)&Kpk[t * 8] = *(const us8*)(p + 8);
    } else if (t == 128) {
        us8 z = {0,0,0,0,0,0,0,0};
        *(us8*)&Qpk[128 * 8] = z;
        *(us8*)&Kpk[128 * 8] = z;
    }

    const u16* vB = vb16 + ((long)b << 20) + (h << 7);
    {
        int c = t >> 4, s = t & 15;
        int cg = (ch << 5) + c;
        int src = (s & 8) | ((s ^ c) & 7);
        *(us8*)&uu.s.Vs[t << 3] = *(const us8*)&vB[((long)cg << 14) + (src << 3)];
    }

    // finalize inputs (independent; compiler may schedule as it likes)
    float sHreg = sH[(b * 128 + wcol) * 128 + h];
    us4 hA[2];
    long hbase = (((long)(b * 128 + wcol)) * 128 + h) * 64 + (ch << 5) + (kg << 2);
#pragma unroll
    for (int ct = 0; ct < 2; ct++)
        hA[ct] = *(const us4*)&accHt[hbase + ct * 16];
    long obase = ((long)b << 20) + (h << 7);
    float4 xv[2];
#pragma unroll
    for (int p = 0; p < 2; p++) {
        int q = t + 512 * p;
        int c = (ch << 5) + (q >> 5), w4 = (q & 31) << 2;
        xv[p] = *(const float4*)&x[obase + ((long)c << 14) + w4];
    }
    __syncthreads();

    f32x4 zero4 = {0.f, 0.f, 0.f, 0.f};

    // ---- QK^T (full E, no mask) ----
    int gt = wv;
    bf16x8 afr;
    { int sl = (kg == 0) ? (gt * 16 + m16) : 128;
      afr = *(const bf16x8*)&Kpk[sl * 8]; }
    int kgr = ((gt & 1) << 1) | (kg >> 1);
    int jb  = (kg & 1) << 2;
#pragma unroll
    for (int ht = 0; ht < 8; ht++) {
        int slB = (kg == 0) ? (ht * 16 + m16) : 128;
        bf16x8 bfr = *(const bf16x8*)&Qpk[slB * 8];
        f32x4 e = __builtin_amdgcn_mfma_f32_16x16x32_bf16(afr, bfr, zero4, 0, 0, 0);
        u16 u0[4];
#pragma unroll
        for (int r = 0; r < 4; r++) u0[r] = f2bf(__expf(e[r]));
        int eidx = ((((ht << 2) | (gt >> 1)) * 64 + kgr * 16 + m16) << 3) + jb;
        u32x2 pk2;
        pk2.x = (unsigned)u0[0] | ((unsigned)u0[1] << 16);
        pk2.y = (unsigned)u0[2] | ((unsigned)u0[3] << 16);
        *(u32x2*)&uu.s.Epk[eidx] = pk2;
    }
    __syncthreads();

    // ---- PV half: D[c(32)][w] ----
    int mt = wv;
    bf16x8 bE[4];
#pragma unroll
    for (int kt = 0; kt < 4; kt++)
        bE[kt] = *(const bf16x8*)&uu.s.Epk[(((mt << 2) + kt) * 64 + l) << 3];

    bf16x8 ones;
    short ov = (m16 == 0) ? (short)0x3F80 : (short)0;
#pragma unroll
    for (int j = 0; j < 8; j++) ones[j] = ov;

    f32x4 acc[3];
#pragma unroll
    for (int i = 0; i < 3; i++) acc[i] = zero4;

#pragma unroll
    for (int ct = 0; ct < 2; ct++) {
#pragma unroll
        for (int kt = 0; kt < 4; kt++) {
            int slot = ((ct * 16 + m16) << 4) | ((((kt << 2) | kg)) ^ (m16 & 7));
            bf16x8 aV = *(const bf16x8*)&uu.s.Vs[slot << 3];
            acc[ct] = __builtin_amdgcn_mfma_f32_16x16x32_bf16(aV, bE[kt], acc[ct], 0, 0, 0);
        }
    }
#pragma unroll
    for (int kt = 0; kt < 4; kt++)
        acc[2] = __builtin_amdgcn_mfma_f32_16x16x32_bf16(ones, bE[kt], acc[2], 0, 0, 0);

    // ---- sW broadcast (lane m16 holds ones-row value for column wcol) ----
    float sWv_ = __shfl(acc[2][0], m16, 64);
    float grv = gm / (sHreg + sWv_);

    __syncthreads();   // Epk/Vs reads done; union flips to outS

    // ---- F0: outS = gr*(accW + accH) ----
#pragma unroll
    for (int ct = 0; ct < 2; ct++) {
#pragma unroll
        for (int r = 0; r < 4; r++)
            uu.f.outS[(ct * 16 + (kg << 2) + r) * 132 + wcol] =
                grv * (acc[ct][r] + bf2f(hA[ct][r]));
    }
    __syncthreads();

    // ---- F3: coalesced out = outS + x ----
#pragma unroll
    for (int p = 0; p < 2; p++) {
        int q = t + 512 * p;
        int cl = q >> 5, w4 = (q & 31) << 2;
        int c = (ch << 5) + cl;
        float4 tv = *(float4*)&uu.f.outS[cl * 132 + w4];
        float4 r;
        r.x = tv.x + xv[p].x;
        r.y = tv.y + xv[p].y;
        r.z = tv.z + xv[p].z;
        r.w = tv.w + xv[p].w;
        *(float4*)&out[obase + ((long)c << 14) + w4] = r;
    }
}

extern "C" void kernel_launch(void* const* d_in, const int* in_sizes, int n_in,
                              void* d_out, int out_size, void* d_ws, size_t ws_size,
                              hipStream_t stream) {
    const float* x     = (const float*)d_in[0];
    const float* Wq    = (const float*)d_in[1];
    const float* bq    = (const float*)d_in[2];
    const float* Wk    = (const float*)d_in[3];
    const float* bk    = (const float*)d_in[4];
    const float* Wv    = (const float*)d_in[5];
    const float* bv    = (const float*)d_in[6];
    const float* gamma = (const float*)d_in[7];
    float* out = (float*)d_out;

    u16* vb16  = (u16*)d_ws;                 // 16,777,216 u16 (32MB)
    u16* vTc   = vb16 + 16777216;            // 16,777,216 u16 (32MB)
    u16* qkTr  = vTc + 16777216;             // 4,194,304 u16 (8MB)
    u16* accHt = qkTr + 4194304;             // 16,777,216 u16 (32MB)
    float* sH  = (float*)(accHt + 16777216); // 262,144 f32 (1MB)
    u16* Wpk   = (u16*)(sH + 262144);        // 5,120 u16
    float* biasf = (float*)(Wpk + 5120);     // 80 f32

    wprep_kernel<<<1, 256, 0, stream>>>(Wq, bq, Wk, bk, Wv, bv, Wpk, biasf);
    proj_kernel<<<1024, 512, 0, stream>>>(x, Wpk, biasf, vb16, qkTr);
    vtrans_kernel<<<16384, 256, 0, stream>>>(vb16, vTc);
    colH_kernel<<<4096, 512, 0, stream>>>(qkTr, vTc, accHt, sH);
    rowW_fin_kernel<<<4096, 512, 0, stream>>>(qkTr, vb16, accHt, sH, x, gamma, out);
}

// Round 9
// 108.011 us; speedup vs baseline: 1.0758x; 1.0758x over previous
//
#include <hip/hip_runtime.h>
#include <hip/hip_bf16.h>

// B=16, C=64, CQ=8, H=W=128
typedef unsigned short u16;
typedef __attribute__((ext_vector_type(8))) short    bf16x8;
typedef __attribute__((ext_vector_type(8))) unsigned short us8;
typedef __attribute__((ext_vector_type(4))) unsigned short us4;
typedef __attribute__((ext_vector_type(4))) float    f32x4;
typedef __attribute__((ext_vector_type(2))) unsigned int u32x2;

__device__ __forceinline__ u16 f2bf(float f) {
    unsigned u = __float_as_uint(f);
    return (u16)((u + 0x7FFFu + ((u >> 16) & 1u)) >> 16);
}
__device__ __forceinline__ float bf2f(u16 v) {
    return __uint_as_float((unsigned)v << 16);
}

// ---------------------------------------------------------------------------
// Kernel 0: W prep. Packs Wv/Wq/Wk into bf16 B-frag slots
// Wpk[nt(5)][kt(2)][lane(64)][8]; biasf[80] = {bv, bq, bk}.
// ---------------------------------------------------------------------------
__global__ __launch_bounds__(256) void wprep_kernel(
    const float* __restrict__ Wq, const float* __restrict__ bq,
    const float* __restrict__ Wk, const float* __restrict__ bk,
    const float* __restrict__ Wv, const float* __restrict__ bv,
    u16* __restrict__ Wpk, float* __restrict__ biasf)
{
    int t = threadIdx.x;
    for (int s = t; s < 640; s += 256) {
        int nt = s >> 7;
        int kt = (s >> 6) & 1;
        int l  = s & 63;
        int n  = (nt << 4) | (l & 15);
        int k0 = kt * 32 + ((l >> 4) << 3);
        const float* row;
        if (n < 64) row = Wv + n * 64;
        else if (n < 72) row = Wq + (n - 64) * 64;
        else row = Wk + (n - 72) * 64;
        us8 o;
#pragma unroll
        for (int j = 0; j < 8; j++) o[j] = f2bf(row[k0 + j]);
        *(us8*)&Wpk[s * 8] = o;
    }
    if (t < 80) {
        float bb;
        if (t < 64) bb = bv[t];
        else if (t < 72) bb = bq[t - 64];
        else bb = bk[t - 72];
        biasf[t] = bb;
    }
}

// ---------------------------------------------------------------------------
// Kernel 1: projections via MFMA. Block = 256 pixels, 512 thr = 8 waves.
// ---------------------------------------------------------------------------
#define PH 258   // LDS x-tile row stride (u16); ==2 mod 4 -> conflict-free frags
__global__ __launch_bounds__(512) void proj_kernel(
    const float* __restrict__ x, const u16* __restrict__ Wpk,
    const float* __restrict__ biasf,
    u16* __restrict__ vb16, u16* __restrict__ qkTr)
{
    __shared__ u16 Xh[64 * PH];   // 33 KB

    int t = threadIdx.x;
    int bid = blockIdx.x;
    int wg = ((bid & 7) << 7) | (bid >> 3);   // b-matched XCD swizzle
    int b = wg >> 6;
    int hw0 = (wg & 63) << 8;
    const float* xb = x + ((long)b << 20) + hw0;

#pragma unroll
    for (int it = 0; it < 8; it++) {
        int c = it * 8 + (t >> 6);
        int pix = (t & 63) << 2;
        float4 xv = *(const float4*)&xb[(c << 14) + pix];
        unsigned lo = ((unsigned)f2bf(xv.y) << 16) | f2bf(xv.x);
        unsigned hi = ((unsigned)f2bf(xv.w) << 16) | f2bf(xv.z);
        unsigned* dst = (unsigned*)&Xh[c * PH + pix];
        dst[0] = lo; dst[1] = hi;
    }
    __syncthreads();

    int wv = t >> 6, l = t & 63;
    int m16 = l & 15, kg = l >> 4;
    int pixb = wv << 5;

    bf16x8 af[2][2];
#pragma unroll
    for (int mt = 0; mt < 2; mt++) {
        int pix = pixb + (mt << 4) + m16;
#pragma unroll
        for (int kt = 0; kt < 2; kt++) {
            us8 a;
#pragma unroll
            for (int j = 0; j < 8; j++)
                a[j] = Xh[(kt * 32 + (kg << 3) + j) * PH + pix];
            af[mt][kt] = (bf16x8)a;
        }
    }

    f32x4 acc[2][5];
#pragma unroll
    for (int nt = 0; nt < 5; nt++) {
        float bb = biasf[(nt << 4) + m16];
        f32x4 binit = {bb, bb, bb, bb};
        bf16x8 b0 = *(const bf16x8*)&Wpk[(((nt << 1) + 0) << 9) + (l << 3)];
        bf16x8 b1 = *(const bf16x8*)&Wpk[(((nt << 1) + 1) << 9) + (l << 3)];
#pragma unroll
        for (int mt = 0; mt < 2; mt++) {
            f32x4 a_ = binit;
            a_ = __builtin_amdgcn_mfma_f32_16x16x32_bf16(af[mt][0], b0, a_, 0, 0, 0);
            a_ = __builtin_amdgcn_mfma_f32_16x16x32_bf16(af[mt][1], b1, a_, 0, 0, 0);
            acc[mt][nt] = a_;
        }
    }

    long vbase = ((long)b << 20) + hw0;
#pragma unroll
    for (int mt = 0; mt < 2; mt++) {
        int pix0 = pixb + (mt << 4) + (kg << 2);
#pragma unroll
        for (int nt = 0; nt < 4; nt++) {
            int c = (nt << 4) + m16;
            us4 pkd = { f2bf(acc[mt][nt][0]), f2bf(acc[mt][nt][1]),
                        f2bf(acc[mt][nt][2]), f2bf(acc[mt][nt][3]) };
            *(us4*)&vb16[vbase + (c << 14) + pix0] = pkd;
        }
#pragma unroll
        for (int r = 0; r < 4; r++)
            qkTr[((((long)(b << 14)) + hw0 + pix0 + r) << 4) + m16] = f2bf(acc[mt][4][r]);
    }
}

// ---------------------------------------------------------------------------
// Kernel 2: v transpose: vb16[b][c][g][w] -> vTc[b][w][c][g] (bf16).
// ---------------------------------------------------------------------------
__global__ __launch_bounds__(256) void vtrans_kernel(
    const u16* __restrict__ vb16, u16* __restrict__ vTc)
{
    __shared__ u16 tile[32][33];
    int t = threadIdx.x;
    int bid = blockIdx.x;
    int vwg = ((bid & 7) << 11) | (bid >> 3);  // b-matched XCD swizzle
    int b = vwg >> 10;
    int c = (vwg >> 4) & 63;
    int g0 = ((vwg >> 2) & 3) * 32, w0 = (vwg & 3) * 32;
    const u16* src = vb16 + ((b * 64 + c) << 14);
#pragma unroll
    for (int it = 0; it < 4; it++) {
        int i = it * 8 + (t >> 5), j = t & 31;
        tile[i][j] = src[(g0 + i) * 128 + w0 + j];
    }
    __syncthreads();
    int j = t >> 3, i4 = (t & 7) * 4;
    us4 o = { tile[i4][j], tile[i4 + 1][j], tile[i4 + 2][j], tile[i4 + 3][j] };
    *(us4*)&vTc[((b * 128 + w0 + j) * 64 + c) * 128 + g0 + i4] = o;
}

// ---------------------------------------------------------------------------
// Kernel 3: column attention, h-split. Block (b, w, hh); 4096 blocks.
// E[g(128)][h-half(64)] (diag mask) -> Epk; PV D[c(64)+ones][h-half].
// Writes accHt[b][w][h][c] bf16 + sH[b][w][h].
// ---------------------------------------------------------------------------
__global__ __launch_bounds__(512) void colH_kernel(
    const u16* __restrict__ qkTr, const u16* __restrict__ vTc,
    u16* __restrict__ accHt, float* __restrict__ sH)
{
    __shared__ u16 Qpk[65 * 8];        // h-half Q + zero slot 64
    __shared__ u16 Kpk[129 * 8];       // full column K + zero slot 128
    __shared__ u16 Epk[1024 * 8];      // 16 KB: [16 slot-groups][64 lanes][8]
    __shared__ u16 Vs[1024 * 8];       // 16 KB: V^T tile, XOR-swizzled src

    int t = threadIdx.x;
    int bid = blockIdx.x;
    int wg = ((bid & 7) << 9) | (bid >> 3);   // bijective, b-contiguous per XCD
    int b = wg >> 8, w = (wg >> 1) & 127, hh = wg & 1;
    int h0 = hh << 6;

    if (t < 64) {
        const u16* p = qkTr + (((long)((b << 14) + (h0 + t) * 128 + w)) << 4);
        *(us8*)&Qpk[t * 8] = *(const us8*)p;
    } else if (t == 64) {
        us8 z = {0,0,0,0,0,0,0,0};
        *(us8*)&Qpk[64 * 8] = z;
    } else if (t >= 128 && t < 256) {
        const u16* p = qkTr + (((long)((b << 14) + (t - 128) * 128 + w)) << 4);
        *(us8*)&Kpk[(t - 128) * 8] = *(const us8*)(p + 8);
    } else if (t == 256) {
        us8 z = {0,0,0,0,0,0,0,0};
        *(us8*)&Kpk[128 * 8] = z;
    }

    const u16* vB = vTc + (((long)(b * 128 + w)) << 13);
#pragma unroll
    for (int m = t; m < 1024; m += 512) {
        int c = m >> 4, s = m & 15;
        int src = (c << 4) | (s & 8) | ((s ^ c) & 7);
        *(us8*)&Vs[m << 3] = *(const us8*)&vB[src << 3];
    }
    __syncthreads();

    int wv = t >> 6, l = t & 63;
    int m16 = l & 15, kg = l >> 4;
    f32x4 zero4 = {0.f, 0.f, 0.f, 0.f};

    // ---- QK^T: wave owns g-tile gt=wv; E[g][h0+ht*16+m16], 4 ht ----
    int gt = wv;
    bf16x8 afr;
    { int sl = (kg == 0) ? (gt * 16 + m16) : 128;
      afr = *(const bf16x8*)&Kpk[sl * 8]; }
    int kgr = ((gt & 1) << 1) | (kg >> 1);
    int jb  = (kg & 1) << 2;
    int gbase = gt * 16 + kg * 4;
#pragma unroll
    for (int ht = 0; ht < 4; ht++) {
        int slB = (kg == 0) ? (ht * 16 + m16) : 64;
        bf16x8 bfr = *(const bf16x8*)&Qpk[slB * 8];
        f32x4 e = __builtin_amdgcn_mfma_f32_16x16x32_bf16(afr, bfr, zero4, 0, 0, 0);
        u16 u0[4];
#pragma unroll
        for (int r = 0; r < 4; r++) {
            int g = gbase + r, h = h0 + ht * 16 + m16;
            float val = (g == h) ? 0.f : __expf(e[r]);
            u0[r] = f2bf(val);
        }
        int eidx = ((((ht << 2) | (gt >> 1)) * 64 + kgr * 16 + m16) << 3) + jb;
        u32x2 pk2;
        pk2.x = (unsigned)u0[0] | ((unsigned)u0[1] << 16);
        pk2.y = (unsigned)u0[2] | ((unsigned)u0[3] << 16);
        *(u32x2*)&Epk[eidx] = pk2;
    }
    __syncthreads();

    // ---- PV: wave (cp, hq): c-tiles {2cp,2cp+1}, h-tile hq ----
    int cp = wv >> 2, hq = wv & 3;
    bf16x8 bE[4];
#pragma unroll
    for (int kt = 0; kt < 4; kt++)
        bE[kt] = *(const bf16x8*)&Epk[(((hq << 2) + kt) * 64 + l) << 3];

    f32x4 acc[2];
    acc[0] = zero4; acc[1] = zero4;
#pragma unroll
    for (int ci = 0; ci < 2; ci++) {
        int ct = cp * 2 + ci;
#pragma unroll
        for (int kt = 0; kt < 4; kt++) {
            int slot = ((ct * 16 + m16) << 4) | ((((kt << 2) | kg)) ^ (m16 & 7));
            bf16x8 aV = *(const bf16x8*)&Vs[slot << 3];
            acc[ci] = __builtin_amdgcn_mfma_f32_16x16x32_bf16(aV, bE[kt], acc[ci], 0, 0, 0);
        }
    }
    f32x4 accS = zero4;
    if (cp == 0) {
        bf16x8 ones;
        short ov = (m16 == 0) ? (short)0x3F80 : (short)0;
#pragma unroll
        for (int j = 0; j < 8; j++) ones[j] = ov;
#pragma unroll
        for (int kt = 0; kt < 4; kt++)
            accS = __builtin_amdgcn_mfma_f32_16x16x32_bf16(ones, bE[kt], accS, 0, 0, 0);
    }

    int hcol = h0 + hq * 16 + m16;
    long obase = (((long)(b * 128 + w)) * 128 + hcol) * 64 + cp * 32;
#pragma unroll
    for (int ci = 0; ci < 2; ci++) {
        us4 pkd = { f2bf(acc[ci][0]), f2bf(acc[ci][1]), f2bf(acc[ci][2]), f2bf(acc[ci][3]) };
        *(us4*)&accHt[obase + ci * 16 + kg * 4] = pkd;
    }
    if (cp == 0 && kg == 0)
        sH[(b * 128 + w) * 128 + hcol] = accS[0];
}

// ---------------------------------------------------------------------------
// Kernel 4: row attention + fused finalize, w-split. Block (b, h, wh).
// E[v(128)][w-half(64)] -> Epk; PV D[c+ones][w-half]; finalize from regs.
// ---------------------------------------------------------------------------
__global__ __launch_bounds__(512) void rowW_fin_kernel(
    const u16* __restrict__ qkTr, const u16* __restrict__ vb16,
    const u16* __restrict__ accHt, const float* __restrict__ sH,
    const float* __restrict__ x, const float* __restrict__ gamma,
    float* __restrict__ out)
{
    __shared__ u16 Qpk[65 * 8];
    __shared__ u16 Kpk[129 * 8];
    __shared__ union FU {
        struct { u16 Epk[1024 * 8]; u16 Vs[1024 * 8]; } s;   // 32 KB
        struct { float outS[64 * 68]; } f;                    // 17.4 KB
    } uu;

    int t = threadIdx.x;
    int bid = blockIdx.x;
    int wg = ((bid & 7) << 9) | (bid >> 3);
    int b = wg >> 8, h = (wg >> 1) & 127, wh = wg & 1;
    int w0 = wh << 6;
    float gm = gamma[0];

    if (t < 64) {
        const u16* p = qkTr + (((long)((b << 14) + h * 128 + w0 + t)) << 4);
        *(us8*)&Qpk[t * 8] = *(const us8*)p;
    } else if (t == 64) {
        us8 z = {0,0,0,0,0,0,0,0};
        *(us8*)&Qpk[64 * 8] = z;
    } else if (t >= 128 && t < 256) {
        const u16* p = qkTr + (((long)((b << 14) + h * 128 + (t - 128))) << 4);
        *(us8*)&Kpk[(t - 128) * 8] = *(const us8*)(p + 8);
    } else if (t == 256) {
        us8 z = {0,0,0,0,0,0,0,0};
        *(us8*)&Kpk[128 * 8] = z;
    }

    const u16* vB = vb16 + ((long)b << 20) + (h << 7);
#pragma unroll
    for (int m = t; m < 1024; m += 512) {
        int c = m >> 4, s = m & 15;
        int src = (s & 8) | ((s ^ c) & 7);
        *(us8*)&uu.s.Vs[m << 3] = *(const us8*)&vB[((long)c << 14) + (src << 3)];
    }
    __syncthreads();

    int wv = t >> 6, l = t & 63;
    int m16 = l & 15, kg = l >> 4;
    f32x4 zero4 = {0.f, 0.f, 0.f, 0.f};

    // ---- QK^T: wave owns v-tile gt=wv; E[v][w0+ht*16+m16], 4 ht, no mask ----
    int gt = wv;
    bf16x8 afr;
    { int sl = (kg == 0) ? (gt * 16 + m16) : 128;
      afr = *(const bf16x8*)&Kpk[sl * 8]; }
    int kgr = ((gt & 1) << 1) | (kg >> 1);
    int jb  = (kg & 1) << 2;
#pragma unroll
    for (int ht = 0; ht < 4; ht++) {
        int slB = (kg == 0) ? (ht * 16 + m16) : 64;
        bf16x8 bfr = *(const bf16x8*)&Qpk[slB * 8];
        f32x4 e = __builtin_amdgcn_mfma_f32_16x16x32_bf16(afr, bfr, zero4, 0, 0, 0);
        u16 u0[4];
#pragma unroll
        for (int r = 0; r < 4; r++) u0[r] = f2bf(__expf(e[r]));
        int eidx = ((((ht << 2) | (gt >> 1)) * 64 + kgr * 16 + m16) << 3) + jb;
        u32x2 pk2;
        pk2.x = (unsigned)u0[0] | ((unsigned)u0[1] << 16);
        pk2.y = (unsigned)u0[2] | ((unsigned)u0[3] << 16);
        *(u32x2*)&uu.s.Epk[eidx] = pk2;
    }
    __syncthreads();

    // ---- PV: wave (cp, hq): c-tiles {2cp,2cp+1}, w-tile hq ----
    int cp = wv >> 2, hq = wv & 3;
    bf16x8 bE[4];
#pragma unroll
    for (int kt = 0; kt < 4; kt++)
        bE[kt] = *(const bf16x8*)&uu.s.Epk[(((hq << 2) + kt) * 64 + l) << 3];

    f32x4 acc[2];
    acc[0] = zero4; acc[1] = zero4;
#pragma unroll
    for (int ci = 0; ci < 2; ci++) {
        int ct = cp * 2 + ci;
#pragma unroll
        for (int kt = 0; kt < 4; kt++) {
            int slot = ((ct * 16 + m16) << 4) | ((((kt << 2) | kg)) ^ (m16 & 7));
            bf16x8 aV = *(const bf16x8*)&uu.s.Vs[slot << 3];
            acc[ci] = __builtin_amdgcn_mfma_f32_16x16x32_bf16(aV, bE[kt], acc[ci], 0, 0, 0);
        }
    }
    // ones row duplicated on BOTH cp halves so the sW shfl stays wave-local
    f32x4 accS = zero4;
    {
        bf16x8 ones;
        short ov = (m16 == 0) ? (short)0x3F80 : (short)0;
#pragma unroll
        for (int j = 0; j < 8; j++) ones[j] = ov;
#pragma unroll
        for (int kt = 0; kt < 4; kt++)
            accS = __builtin_amdgcn_mfma_f32_16x16x32_bf16(ones, bE[kt], accS, 0, 0, 0);
    }

    int wcol = hq * 16 + m16;              // w within half
    float sWv_ = __shfl(accS[0], m16, 64); // D[0][m16] lives in lane m16 (kg=0)
    float sHreg = sH[((long)(b * 128 + w0 + wcol)) * 128 + h];
    float grv = gm / (sHreg + sWv_);

    // accHt slice for this lane's (w, c-rows)
    us4 hA[2];
    long hbase = (((long)(b * 128 + w0 + wcol)) * 128 + h) * 64 + cp * 32 + (kg << 2);
#pragma unroll
    for (int ci = 0; ci < 2; ci++)
        hA[ci] = *(const us4*)&accHt[hbase + ci * 16];

    __syncthreads();   // Epk/Vs reads done; union flips to outS

    // ---- F0: outS = gr*(accW + accH) ----
#pragma unroll
    for (int ci = 0; ci < 2; ci++) {
#pragma unroll
        for (int r = 0; r < 4; r++)
            uu.f.outS[((cp * 2 + ci) * 16 + (kg << 2) + r) * 68 + wcol] =
                grv * (acc[ci][r] + bf2f(hA[ci][r]));
    }
    __syncthreads();

    // ---- F3: coalesced out = outS + x ----
    long obase = ((long)b << 20) + (h << 7) + w0;
#pragma unroll
    for (int p = 0; p < 2; p++) {
        int q = t + 512 * p;
        int c = q >> 4, w4 = (q & 15) << 2;
        long ga = obase + ((long)c << 14) + w4;
        float4 tv = *(float4*)&uu.f.outS[c * 68 + w4];
        float4 xv = *(const float4*)&x[ga];
        float4 r;
        r.x = tv.x + xv.x;
        r.y = tv.y + xv.y;
        r.z = tv.z + xv.z;
        r.w = tv.w + xv.w;
        *(float4*)&out[ga] = r;
    }
}

extern "C" void kernel_launch(void* const* d_in, const int* in_sizes, int n_in,
                              void* d_out, int out_size, void* d_ws, size_t ws_size,
                              hipStream_t stream) {
    const float* x     = (const float*)d_in[0];
    const float* Wq    = (const float*)d_in[1];
    const float* bq    = (const float*)d_in[2];
    const float* Wk    = (const float*)d_in[3];
    const float* bk    = (const float*)d_in[4];
    const float* Wv    = (const float*)d_in[5];
    const float* bv    = (const float*)d_in[6];
    const float* gamma = (const float*)d_in[7];
    float* out = (float*)d_out;

    u16* vb16  = (u16*)d_ws;                 // 16,777,216 u16 (32MB)
    u16* vTc   = vb16 + 16777216;            // 16,777,216 u16 (32MB)
    u16* qkTr  = vTc + 16777216;             // 4,194,304 u16 (8MB)
    u16* accHt = qkTr + 4194304;             // 16,777,216 u16 (32MB)
    float* sH  = (float*)(accHt + 16777216); // 262,144 f32 (1MB)
    u16* Wpk   = (u16*)(sH + 262144);        // 5,120 u16
    float* biasf = (float*)(Wpk + 5120);     // 80 f32

    wprep_kernel<<<1, 256, 0, stream>>>(Wq, bq, Wk, bk, Wv, bv, Wpk, biasf);
    proj_kernel<<<1024, 512, 0, stream>>>(x, Wpk, biasf, vb16, qkTr);
    vtrans_kernel<<<16384, 256, 0, stream>>>(vb16, vTc);
    colH_kernel<<<4096, 512, 0, stream>>>(qkTr, vTc, accHt, sH);
    rowW_fin_kernel<<<4096, 512, 0, stream>>>(qkTr, vb16, accHt, sH, x, gamma, out);
}

// Round 10
// 104.248 us; speedup vs baseline: 1.1147x; 1.0361x over previous
//
#include <hip/hip_runtime.h>
#include <hip/hip_bf16.h>

// B=16, C=64, CQ=8, H=W=128
typedef unsigned short u16;
typedef __attribute__((ext_vector_type(8))) short    bf16x8;
typedef __attribute__((ext_vector_type(8))) unsigned short us8;
typedef __attribute__((ext_vector_type(4))) unsigned short us4;
typedef __attribute__((ext_vector_type(4))) float    f32x4;
typedef __attribute__((ext_vector_type(2))) unsigned int u32x2;

__device__ __forceinline__ u16 f2bf(float f) {
    unsigned u = __float_as_uint(f);
    return (u16)((u + 0x7FFFu + ((u >> 16) & 1u)) >> 16);
}
__device__ __forceinline__ float bf2f(u16 v) {
    return __uint_as_float((unsigned)v << 16);
}

// ---------------------------------------------------------------------------
// Kernel 0: W prep. Packs Wv/Wq/Wk into bf16 B-frag slots
// Wpk[nt(5)][kt(2)][lane(64)][8]; biasf[80] = {bv, bq, bk}.
// ---------------------------------------------------------------------------
__global__ __launch_bounds__(256) void wprep_kernel(
    const float* __restrict__ Wq, const float* __restrict__ bq,
    const float* __restrict__ Wk, const float* __restrict__ bk,
    const float* __restrict__ Wv, const float* __restrict__ bv,
    u16* __restrict__ Wpk, float* __restrict__ biasf)
{
    int t = threadIdx.x;
    for (int s = t; s < 640; s += 256) {
        int nt = s >> 7;
        int kt = (s >> 6) & 1;
        int l  = s & 63;
        int n  = (nt << 4) | (l & 15);
        int k0 = kt * 32 + ((l >> 4) << 3);
        const float* row;
        if (n < 64) row = Wv + n * 64;
        else if (n < 72) row = Wq + (n - 64) * 64;
        else row = Wk + (n - 72) * 64;
        us8 o;
#pragma unroll
        for (int j = 0; j < 8; j++) o[j] = f2bf(row[k0 + j]);
        *(us8*)&Wpk[s * 8] = o;
    }
    if (t < 80) {
        float bb;
        if (t < 64) bb = bv[t];
        else if (t < 72) bb = bq[t - 64];
        else bb = bk[t - 72];
        biasf[t] = bb;
    }
}

// ---------------------------------------------------------------------------
// Kernel 1: projections via MFMA. Block = 256 pixels, 512 thr = 8 waves.
// ---------------------------------------------------------------------------
#define PH 258   // LDS x-tile row stride (u16); ==2 mod 4 -> conflict-free frags
__global__ __launch_bounds__(512) void proj_kernel(
    const float* __restrict__ x, const u16* __restrict__ Wpk,
    const float* __restrict__ biasf,
    u16* __restrict__ vb16, u16* __restrict__ qkTr)
{
    __shared__ u16 Xh[64 * PH];   // 33 KB

    int t = threadIdx.x;
    int bid = blockIdx.x;
    int wg = ((bid & 7) << 7) | (bid >> 3);   // b-matched XCD swizzle
    int b = wg >> 6;
    int hw0 = (wg & 63) << 8;
    const float* xb = x + ((long)b << 20) + hw0;

#pragma unroll
    for (int it = 0; it < 8; it++) {
        int c = it * 8 + (t >> 6);
        int pix = (t & 63) << 2;
        float4 xv = *(const float4*)&xb[(c << 14) + pix];
        unsigned lo = ((unsigned)f2bf(xv.y) << 16) | f2bf(xv.x);
        unsigned hi = ((unsigned)f2bf(xv.w) << 16) | f2bf(xv.z);
        unsigned* dst = (unsigned*)&Xh[c * PH + pix];
        dst[0] = lo; dst[1] = hi;
    }
    __syncthreads();

    int wv = t >> 6, l = t & 63;
    int m16 = l & 15, kg = l >> 4;
    int pixb = wv << 5;

    bf16x8 af[2][2];
#pragma unroll
    for (int mt = 0; mt < 2; mt++) {
        int pix = pixb + (mt << 4) + m16;
#pragma unroll
        for (int kt = 0; kt < 2; kt++) {
            us8 a;
#pragma unroll
            for (int j = 0; j < 8; j++)
                a[j] = Xh[(kt * 32 + (kg << 3) + j) * PH + pix];
            af[mt][kt] = (bf16x8)a;
        }
    }

    f32x4 acc[2][5];
#pragma unroll
    for (int nt = 0; nt < 5; nt++) {
        float bb = biasf[(nt << 4) + m16];
        f32x4 binit = {bb, bb, bb, bb};
        bf16x8 b0 = *(const bf16x8*)&Wpk[(((nt << 1) + 0) << 9) + (l << 3)];
        bf16x8 b1 = *(const bf16x8*)&Wpk[(((nt << 1) + 1) << 9) + (l << 3)];
#pragma unroll
        for (int mt = 0; mt < 2; mt++) {
            f32x4 a_ = binit;
            a_ = __builtin_amdgcn_mfma_f32_16x16x32_bf16(af[mt][0], b0, a_, 0, 0, 0);
            a_ = __builtin_amdgcn_mfma_f32_16x16x32_bf16(af[mt][1], b1, a_, 0, 0, 0);
            acc[mt][nt] = a_;
        }
    }

    long vbase = ((long)b << 20) + hw0;
#pragma unroll
    for (int mt = 0; mt < 2; mt++) {
        int pix0 = pixb + (mt << 4) + (kg << 2);
#pragma unroll
        for (int nt = 0; nt < 4; nt++) {
            int c = (nt << 4) + m16;
            us4 pkd = { f2bf(acc[mt][nt][0]), f2bf(acc[mt][nt][1]),
                        f2bf(acc[mt][nt][2]), f2bf(acc[mt][nt][3]) };
            *(us4*)&vb16[vbase + (c << 14) + pix0] = pkd;
        }
#pragma unroll
        for (int r = 0; r < 4; r++)
            qkTr[((((long)(b << 14)) + hw0 + pix0 + r) << 4) + m16] = f2bf(acc[mt][4][r]);
    }
}

// ---------------------------------------------------------------------------
// Kernel 2: v transpose: vb16[b][c][g][w] -> vTc[b][w][c][g] (bf16).
// ---------------------------------------------------------------------------
__global__ __launch_bounds__(256) void vtrans_kernel(
    const u16* __restrict__ vb16, u16* __restrict__ vTc)
{
    __shared__ u16 tile[32][33];
    int t = threadIdx.x;
    int bid = blockIdx.x;
    int vwg = ((bid & 7) << 11) | (bid >> 3);  // b-matched XCD swizzle
    int b = vwg >> 10;
    int c = (vwg >> 4) & 63;
    int g0 = ((vwg >> 2) & 3) * 32, w0 = (vwg & 3) * 32;
    const u16* src = vb16 + ((b * 64 + c) << 14);
#pragma unroll
    for (int it = 0; it < 4; it++) {
        int i = it * 8 + (t >> 5), j = t & 31;
        tile[i][j] = src[(g0 + i) * 128 + w0 + j];
    }
    __syncthreads();
    int j = t >> 3, i4 = (t & 7) * 4;
    us4 o = { tile[i4][j], tile[i4 + 1][j], tile[i4 + 2][j], tile[i4 + 3][j] };
    *(us4*)&vTc[((b * 128 + w0 + j) * 64 + c) * 128 + g0 + i4] = o;
}

// ---------------------------------------------------------------------------
// Kernel 3: column attention, h-split. Block (b, w, hh); 4096 blocks.
// E[g(128)][h-half(64)] (diag mask) -> Epk; PV D[c(64)+ones][h-half].
// Writes accHt[b][w][h][c] bf16 + sH[b][w][h].
// ---------------------------------------------------------------------------
__global__ __launch_bounds__(512) void colH_kernel(
    const u16* __restrict__ qkTr, const u16* __restrict__ vTc,
    u16* __restrict__ accHt, float* __restrict__ sH)
{
    __shared__ u16 Qpk[65 * 8];        // h-half Q + zero slot 64
    __shared__ u16 Kpk[129 * 8];       // full column K + zero slot 128
    __shared__ u16 Epk[1024 * 8];      // 16 KB: [16 slot-groups][64 lanes][8]
    __shared__ u16 Vs[1024 * 8];       // 16 KB: V^T tile, XOR-swizzled src

    int t = threadIdx.x;
    int bid = blockIdx.x;
    int wg = ((bid & 7) << 9) | (bid >> 3);   // bijective, b-contiguous per XCD
    int b = wg >> 8, w = (wg >> 1) & 127, hh = wg & 1;
    int h0 = hh << 6;

    if (t < 64) {
        const u16* p = qkTr + (((long)((b << 14) + (h0 + t) * 128 + w)) << 4);
        *(us8*)&Qpk[t * 8] = *(const us8*)p;
    } else if (t == 64) {
        us8 z = {0,0,0,0,0,0,0,0};
        *(us8*)&Qpk[64 * 8] = z;
    } else if (t >= 128 && t < 256) {
        const u16* p = qkTr + (((long)((b << 14) + (t - 128) * 128 + w)) << 4);
        *(us8*)&Kpk[(t - 128) * 8] = *(const us8*)(p + 8);
    } else if (t == 256) {
        us8 z = {0,0,0,0,0,0,0,0};
        *(us8*)&Kpk[128 * 8] = z;
    }

    const u16* vB = vTc + (((long)(b * 128 + w)) << 13);
#pragma unroll
    for (int m = t; m < 1024; m += 512) {
        int c = m >> 4, s = m & 15;
        int src = (c << 4) | (s & 8) | ((s ^ c) & 7);
        *(us8*)&Vs[m << 3] = *(const us8*)&vB[src << 3];
    }
    __syncthreads();

    int wv = t >> 6, l = t & 63;
    int m16 = l & 15, kg = l >> 4;
    f32x4 zero4 = {0.f, 0.f, 0.f, 0.f};

    // ---- QK^T: wave owns g-tile gt=wv; E[g][h0+ht*16+m16], 4 ht ----
    int gt = wv;
    bf16x8 afr;
    { int sl = (kg == 0) ? (gt * 16 + m16) : 128;
      afr = *(const bf16x8*)&Kpk[sl * 8]; }
    int kgr = ((gt & 1) << 1) | (kg >> 1);
    int jb  = (kg & 1) << 2;
    int gbase = gt * 16 + kg * 4;
#pragma unroll
    for (int ht = 0; ht < 4; ht++) {
        int slB = (kg == 0) ? (ht * 16 + m16) : 64;
        bf16x8 bfr = *(const bf16x8*)&Qpk[slB * 8];
        f32x4 e = __builtin_amdgcn_mfma_f32_16x16x32_bf16(afr, bfr, zero4, 0, 0, 0);
        u16 u0[4];
#pragma unroll
        for (int r = 0; r < 4; r++) {
            int g = gbase + r, h = h0 + ht * 16 + m16;
            float val = (g == h) ? 0.f : __expf(e[r]);
            u0[r] = f2bf(val);
        }
        int eidx = ((((ht << 2) | (gt >> 1)) * 64 + kgr * 16 + m16) << 3) + jb;
        u32x2 pk2;
        pk2.x = (unsigned)u0[0] | ((unsigned)u0[1] << 16);
        pk2.y = (unsigned)u0[2] | ((unsigned)u0[3] << 16);
        *(u32x2*)&Epk[eidx] = pk2;
    }
    __syncthreads();

    // ---- PV: wave (cp, hq): c-tiles {2cp,2cp+1}, h-tile hq ----
    int cp = wv >> 2, hq = wv & 3;
    bf16x8 bE[4];
#pragma unroll
    for (int kt = 0; kt < 4; kt++)
        bE[kt] = *(const bf16x8*)&Epk[(((hq << 2) + kt) * 64 + l) << 3];

    f32x4 acc[2];
    acc[0] = zero4; acc[1] = zero4;
#pragma unroll
    for (int ci = 0; ci < 2; ci++) {
        int ct = cp * 2 + ci;
#pragma unroll
        for (int kt = 0; kt < 4; kt++) {
            int slot = ((ct * 16 + m16) << 4) | ((((kt << 2) | kg)) ^ (m16 & 7));
            bf16x8 aV = *(const bf16x8*)&Vs[slot << 3];
            acc[ci] = __builtin_amdgcn_mfma_f32_16x16x32_bf16(aV, bE[kt], acc[ci], 0, 0, 0);
        }
    }
    f32x4 accS = zero4;
    if (cp == 0) {
        bf16x8 ones;
        short ov = (m16 == 0) ? (short)0x3F80 : (short)0;
#pragma unroll
        for (int j = 0; j < 8; j++) ones[j] = ov;
#pragma unroll
        for (int kt = 0; kt < 4; kt++)
            accS = __builtin_amdgcn_mfma_f32_16x16x32_bf16(ones, bE[kt], accS, 0, 0, 0);
    }

    int hcol = h0 + hq * 16 + m16;
    long obase = (((long)(b * 128 + w)) * 128 + hcol) * 64 + cp * 32;
#pragma unroll
    for (int ci = 0; ci < 2; ci++) {
        us4 pkd = { f2bf(acc[ci][0]), f2bf(acc[ci][1]), f2bf(acc[ci][2]), f2bf(acc[ci][3]) };
        *(us4*)&accHt[obase + ci * 16 + kg * 4] = pkd;
    }
    if (cp == 0 && kg == 0)
        sH[(b * 128 + w) * 128 + hcol] = accS[0];
}

// ---------------------------------------------------------------------------
// Kernel 4: row attention + fused finalize, w-split. Block (b, h, wh).
// Finalize inputs loaded at kernel start and PINNED live (asm) so hipcc
// cannot sink them past the staging barrier. Direct-from-register epilogue
// (no outS LDS stage): 2 barriers total.
// ---------------------------------------------------------------------------
__global__ __launch_bounds__(512) void rowW_fin_kernel(
    const u16* __restrict__ qkTr, const u16* __restrict__ vb16,
    const u16* __restrict__ accHt, const float* __restrict__ sH,
    const float* __restrict__ x, const float* __restrict__ gamma,
    float* __restrict__ out)
{
    __shared__ u16 Qpk[65 * 8];
    __shared__ u16 Kpk[129 * 8];
    __shared__ u16 Epk[1024 * 8];   // 16 KB
    __shared__ u16 Vs[1024 * 8];    // 16 KB

    int t = threadIdx.x;
    int bid = blockIdx.x;
    int wg = ((bid & 7) << 9) | (bid >> 3);
    int b = wg >> 8, h = (wg >> 1) & 127, wh = wg & 1;
    int w0 = wh << 6;
    float gm = gamma[0];

    int wv = t >> 6, l = t & 63;
    int m16 = l & 15, kg = l >> 4;
    int cp = wv >> 2, hq = wv & 3;
    int wcol = hq * 16 + m16;          // w within half
    int wfull = w0 + wcol;

    // ---- hoisted finalize loads ----
    float sHreg = sH[((long)(b * 128 + wfull)) * 128 + h];
    us4 hA0, hA1;
    {
        long hbase = (((long)(b * 128 + wfull)) * 128 + h) * 64 + cp * 32 + (kg << 2);
        hA0 = *(const us4*)&accHt[hbase];
        hA1 = *(const us4*)&accHt[hbase + 16];
    }
    long obase = ((long)b << 20) + (h << 7) + wfull;
    float xr[2][4];
#pragma unroll
    for (int ci = 0; ci < 2; ci++)
#pragma unroll
        for (int r = 0; r < 4; r++)
            xr[ci][r] = x[obase + ((long)(cp * 32 + ci * 16 + (kg << 2) + r) << 14)];

    // ---- staging ----
    if (t < 64) {
        const u16* p = qkTr + (((long)((b << 14) + h * 128 + w0 + t)) << 4);
        *(us8*)&Qpk[t * 8] = *(const us8*)p;
    } else if (t == 64) {
        us8 z = {0,0,0,0,0,0,0,0};
        *(us8*)&Qpk[64 * 8] = z;
    } else if (t >= 128 && t < 256) {
        const u16* p = qkTr + (((long)((b << 14) + h * 128 + (t - 128))) << 4);
        *(us8*)&Kpk[(t - 128) * 8] = *(const us8*)(p + 8);
    } else if (t == 256) {
        us8 z = {0,0,0,0,0,0,0,0};
        *(us8*)&Kpk[128 * 8] = z;
    }

    const u16* vB = vb16 + ((long)b << 20) + (h << 7);
#pragma unroll
    for (int m = t; m < 1024; m += 512) {
        int c = m >> 4, s = m & 15;
        int src = (s & 8) | ((s ^ c) & 7);
        *(us8*)&Vs[m << 3] = *(const us8*)&vB[((long)c << 14) + (src << 3)];
    }

    // keep-alive pins: force the finalize loads to be issued & completed here,
    // not sunk to their uses after PV (rule #17).
    {
        uint2 p0 = *(uint2*)&hA0, p1 = *(uint2*)&hA1;
        asm volatile("" :: "v"(sHreg), "v"(p0.x), "v"(p0.y), "v"(p1.x), "v"(p1.y));
        asm volatile("" :: "v"(xr[0][0]), "v"(xr[0][1]), "v"(xr[0][2]), "v"(xr[0][3]),
                          "v"(xr[1][0]), "v"(xr[1][1]), "v"(xr[1][2]), "v"(xr[1][3]));
    }
    __syncthreads();

    f32x4 zero4 = {0.f, 0.f, 0.f, 0.f};

    // ---- QK^T: wave owns v-tile gt=wv; E[v][w0+ht*16+m16], 4 ht, no mask ----
    int gt = wv;
    bf16x8 afr;
    { int sl = (kg == 0) ? (gt * 16 + m16) : 128;
      afr = *(const bf16x8*)&Kpk[sl * 8]; }
    int kgr = ((gt & 1) << 1) | (kg >> 1);
    int jb  = (kg & 1) << 2;
#pragma unroll
    for (int ht = 0; ht < 4; ht++) {
        int slB = (kg == 0) ? (ht * 16 + m16) : 64;
        bf16x8 bfr = *(const bf16x8*)&Qpk[slB * 8];
        f32x4 e = __builtin_amdgcn_mfma_f32_16x16x32_bf16(afr, bfr, zero4, 0, 0, 0);
        u16 u0[4];
#pragma unroll
        for (int r = 0; r < 4; r++) u0[r] = f2bf(__expf(e[r]));
        int eidx = ((((ht << 2) | (gt >> 1)) * 64 + kgr * 16 + m16) << 3) + jb;
        u32x2 pk2;
        pk2.x = (unsigned)u0[0] | ((unsigned)u0[1] << 16);
        pk2.y = (unsigned)u0[2] | ((unsigned)u0[3] << 16);
        *(u32x2*)&Epk[eidx] = pk2;
    }
    __syncthreads();

    // ---- PV: wave (cp, hq): c-tiles {2cp,2cp+1}, w-tile hq ----
    bf16x8 bE[4];
#pragma unroll
    for (int kt = 0; kt < 4; kt++)
        bE[kt] = *(const bf16x8*)&Epk[(((hq << 2) + kt) * 64 + l) << 3];

    f32x4 acc[2];
    acc[0] = zero4; acc[1] = zero4;
#pragma unroll
    for (int ci = 0; ci < 2; ci++) {
        int ct = cp * 2 + ci;
#pragma unroll
        for (int kt = 0; kt < 4; kt++) {
            int slot = ((ct * 16 + m16) << 4) | ((((kt << 2) | kg)) ^ (m16 & 7));
            bf16x8 aV = *(const bf16x8*)&Vs[slot << 3];
            acc[ci] = __builtin_amdgcn_mfma_f32_16x16x32_bf16(aV, bE[kt], acc[ci], 0, 0, 0);
        }
    }
    // ones row duplicated on BOTH cp halves so the sW shfl stays wave-local
    f32x4 accS = zero4;
    {
        bf16x8 ones;
        short ov = (m16 == 0) ? (short)0x3F80 : (short)0;
#pragma unroll
        for (int j = 0; j < 8; j++) ones[j] = ov;
#pragma unroll
        for (int kt = 0; kt < 4; kt++)
            accS = __builtin_amdgcn_mfma_f32_16x16x32_bf16(ones, bE[kt], accS, 0, 0, 0);
    }

    float sWv_ = __shfl(accS[0], m16, 64); // D[0][m16] lives in lane m16 (kg=0)
    float grv = gm / (sHreg + sWv_);

    // ---- direct-from-register epilogue: out = grv*(accW+accH) + x ----
#pragma unroll
    for (int ci = 0; ci < 2; ci++) {
        us4 hAv = (ci == 0) ? hA0 : hA1;
#pragma unroll
        for (int r = 0; r < 4; r++) {
            long ga = obase + ((long)(cp * 32 + ci * 16 + (kg << 2) + r) << 14);
            out[ga] = grv * (acc[ci][r] + bf2f(hAv[r])) + xr[ci][r];
        }
    }
}

extern "C" void kernel_launch(void* const* d_in, const int* in_sizes, int n_in,
                              void* d_out, int out_size, void* d_ws, size_t ws_size,
                              hipStream_t stream) {
    const float* x     = (const float*)d_in[0];
    const float* Wq    = (const float*)d_in[1];
    const float* bq    = (const float*)d_in[2];
    const float* Wk    = (const float*)d_in[3];
    const float* bk    = (const float*)d_in[4];
    const float* Wv    = (const float*)d_in[5];
    const float* bv    = (const float*)d_in[6];
    const float* gamma = (const float*)d_in[7];
    float* out = (float*)d_out;

    u16* vb16  = (u16*)d_ws;                 // 16,777,216 u16 (32MB)
    u16* vTc   = vb16 + 16777216;            // 16,777,216 u16 (32MB)
    u16* qkTr  = vTc + 16777216;             // 4,194,304 u16 (8MB)
    u16* accHt = qkTr + 4194304;             // 16,777,216 u16 (32MB)
    float* sH  = (float*)(accHt + 16777216); // 262,144 f32 (1MB)
    u16* Wpk   = (u16*)(sH + 262144);        // 5,120 u16
    float* biasf = (float*)(Wpk + 5120);     // 80 f32

    wprep_kernel<<<1, 256, 0, stream>>>(Wq, bq, Wk, bk, Wv, bv, Wpk, biasf);
    proj_kernel<<<1024, 512, 0, stream>>>(x, Wpk, biasf, vb16, qkTr);
    vtrans_kernel<<<16384, 256, 0, stream>>>(vb16, vTc);
    colH_kernel<<<4096, 512, 0, stream>>>(qkTr, vTc, accHt, sH);
    rowW_fin_kernel<<<4096, 512, 0, stream>>>(qkTr, vb16, accHt, sH, x, gamma, out);
}

// Round 11
// 104.158 us; speedup vs baseline: 1.1156x; 1.0009x over previous
//
#include <hip/hip_runtime.h>
#include <hip/hip_bf16.h>

// B=16, C=64, CQ=8, H=W=128
typedef unsigned short u16;
typedef __attribute__((ext_vector_type(8))) short    bf16x8;
typedef __attribute__((ext_vector_type(8))) unsigned short us8;
typedef __attribute__((ext_vector_type(4))) unsigned short us4;
typedef __attribute__((ext_vector_type(4))) float    f32x4;
typedef __attribute__((ext_vector_type(2))) unsigned int u32x2;

__device__ __forceinline__ u16 f2bf(float f) {
    unsigned u = __float_as_uint(f);
    return (u16)((u + 0x7FFFu + ((u >> 16) & 1u)) >> 16);
}
__device__ __forceinline__ float bf2f(u16 v) {
    return __uint_as_float((unsigned)v << 16);
}

// ---------------------------------------------------------------------------
// Kernel 0: W prep. Packs Wv/Wq/Wk into bf16 B-frag slots
// Wpk[nt(5)][kt(2)][lane(64)][8]; biasf[80] = {bv, bq, bk}.
// ---------------------------------------------------------------------------
__global__ __launch_bounds__(256) void wprep_kernel(
    const float* __restrict__ Wq, const float* __restrict__ bq,
    const float* __restrict__ Wk, const float* __restrict__ bk,
    const float* __restrict__ Wv, const float* __restrict__ bv,
    u16* __restrict__ Wpk, float* __restrict__ biasf)
{
    int t = threadIdx.x;
    for (int s = t; s < 640; s += 256) {
        int nt = s >> 7;
        int kt = (s >> 6) & 1;
        int l  = s & 63;
        int n  = (nt << 4) | (l & 15);
        int k0 = kt * 32 + ((l >> 4) << 3);
        const float* row;
        if (n < 64) row = Wv + n * 64;
        else if (n < 72) row = Wq + (n - 64) * 64;
        else row = Wk + (n - 72) * 64;
        us8 o;
#pragma unroll
        for (int j = 0; j < 8; j++) o[j] = f2bf(row[k0 + j]);
        *(us8*)&Wpk[s * 8] = o;
    }
    if (t < 80) {
        float bb;
        if (t < 64) bb = bv[t];
        else if (t < 72) bb = bq[t - 64];
        else bb = bk[t - 72];
        biasf[t] = bb;
    }
}

// ---------------------------------------------------------------------------
// Kernel 1: projections via MFMA — barrier-free streaming version.
// Block = 128 pixels, 256 thr = 4 waves. A-frags loaded directly from x
// (32 dwords/thread, 4x64B segments per instr); no block barrier.
// qkTr stored via 1KB wave-local LDS transpose (DS in-order within wave).
// ---------------------------------------------------------------------------
__global__ __launch_bounds__(256) void proj_kernel(
    const float* __restrict__ x, const u16* __restrict__ Wpk,
    const float* __restrict__ biasf,
    u16* __restrict__ vb16, u16* __restrict__ qkTr)
{
    __shared__ u16 qstage[4][32 * 16];   // 4 KB total, 1 KB per wave

    int t = threadIdx.x;
    int bid = blockIdx.x;
    int wg = ((bid & 7) << 8) | (bid >> 3);   // b-matched XCD swizzle
    int b = wg >> 7;
    int hw0 = (wg & 127) << 7;                // 128-pixel chunk
    const float* xb = x + ((long)b << 20) + hw0;

    int wv = t >> 6, l = t & 63;
    int m16 = l & 15, kg = l >> 4;
    int pixb = wv << 5;

    // ---- A-frags direct from global: A[m=pix][k=c], k = kt*32+kg*8+j ----
    bf16x8 af[2][2];
#pragma unroll
    for (int mt = 0; mt < 2; mt++) {
        int pix = pixb + (mt << 4) + m16;
#pragma unroll
        for (int kt = 0; kt < 2; kt++) {
            float v[8];
#pragma unroll
            for (int j = 0; j < 8; j++)
                v[j] = xb[((kt * 32 + (kg << 3) + j) << 14) + pix];
            us8 a;
#pragma unroll
            for (int j = 0; j < 8; j++) a[j] = f2bf(v[j]);
            af[mt][kt] = (bf16x8)a;
        }
    }

    f32x4 acc[2][5];
#pragma unroll
    for (int nt = 0; nt < 5; nt++) {
        float bb = biasf[(nt << 4) + m16];
        f32x4 binit = {bb, bb, bb, bb};
        bf16x8 b0 = *(const bf16x8*)&Wpk[(((nt << 1) + 0) << 9) + (l << 3)];
        bf16x8 b1 = *(const bf16x8*)&Wpk[(((nt << 1) + 1) << 9) + (l << 3)];
#pragma unroll
        for (int mt = 0; mt < 2; mt++) {
            f32x4 a_ = binit;
            a_ = __builtin_amdgcn_mfma_f32_16x16x32_bf16(af[mt][0], b0, a_, 0, 0, 0);
            a_ = __builtin_amdgcn_mfma_f32_16x16x32_bf16(af[mt][1], b1, a_, 0, 0, 0);
            acc[mt][nt] = a_;
        }
    }

    // ---- v stores: us4-coalesced, direct from regs ----
    long vbase = ((long)b << 20) + hw0;
#pragma unroll
    for (int mt = 0; mt < 2; mt++) {
        int pix0 = pixb + (mt << 4) + (kg << 2);
#pragma unroll
        for (int nt = 0; nt < 4; nt++) {
            int c = (nt << 4) + m16;
            us4 pkd = { f2bf(acc[mt][nt][0]), f2bf(acc[mt][nt][1]),
                        f2bf(acc[mt][nt][2]), f2bf(acc[mt][nt][3]) };
            *(us4*)&vb16[vbase + (c << 14) + pix0] = pkd;
        }
    }

    // ---- qk store: wave-local LDS transpose -> coalesced us8 store ----
    {
        u16* qs = qstage[wv];
#pragma unroll
        for (int mt = 0; mt < 2; mt++) {
#pragma unroll
            for (int r = 0; r < 4; r++)
                qs[((mt << 4) + (kg << 2) + r) * 16 + m16] = f2bf(acc[mt][4][r]);
        }
        // same-wave DS ordering guarantees visibility; no barrier needed
        int pixl = l >> 1, half = l & 1;
        us8 o = *(us8*)&qs[pixl * 16 + half * 8];
        *(us8*)&qkTr[(((long)((b << 14) + hw0 + pixb + pixl)) << 4) + half * 8] = o;
    }
}

// ---------------------------------------------------------------------------
// Kernel 2: v transpose: vb16[b][c][g][w] -> vTc[b][w][c][g] (bf16).
// ---------------------------------------------------------------------------
__global__ __launch_bounds__(256) void vtrans_kernel(
    const u16* __restrict__ vb16, u16* __restrict__ vTc)
{
    __shared__ u16 tile[32][33];
    int t = threadIdx.x;
    int bid = blockIdx.x;
    int vwg = ((bid & 7) << 11) | (bid >> 3);  // b-matched XCD swizzle
    int b = vwg >> 10;
    int c = (vwg >> 4) & 63;
    int g0 = ((vwg >> 2) & 3) * 32, w0 = (vwg & 3) * 32;
    const u16* src = vb16 + ((b * 64 + c) << 14);
#pragma unroll
    for (int it = 0; it < 4; it++) {
        int i = it * 8 + (t >> 5), j = t & 31;
        tile[i][j] = src[(g0 + i) * 128 + w0 + j];
    }
    __syncthreads();
    int j = t >> 3, i4 = (t & 7) * 4;
    us4 o = { tile[i4][j], tile[i4 + 1][j], tile[i4 + 2][j], tile[i4 + 3][j] };
    *(us4*)&vTc[((b * 128 + w0 + j) * 64 + c) * 128 + g0 + i4] = o;
}

// ---------------------------------------------------------------------------
// Kernel 3: column attention, h-split. Block (b, w, hh); 4096 blocks.
// E[g(128)][h-half(64)] (diag mask) -> Epk; PV D[c(64)+ones][h-half].
// Writes accHt[b][w][h][c] bf16 + sH[b][w][h].
// ---------------------------------------------------------------------------
__global__ __launch_bounds__(512) void colH_kernel(
    const u16* __restrict__ qkTr, const u16* __restrict__ vTc,
    u16* __restrict__ accHt, float* __restrict__ sH)
{
    __shared__ u16 Qpk[65 * 8];        // h-half Q + zero slot 64
    __shared__ u16 Kpk[129 * 8];       // full column K + zero slot 128
    __shared__ u16 Epk[1024 * 8];      // 16 KB
    __shared__ u16 Vs[1024 * 8];       // 16 KB

    int t = threadIdx.x;
    int bid = blockIdx.x;
    int wg = ((bid & 7) << 9) | (bid >> 3);   // bijective, b-contiguous per XCD
    int b = wg >> 8, w = (wg >> 1) & 127, hh = wg & 1;
    int h0 = hh << 6;

    if (t < 64) {
        const u16* p = qkTr + (((long)((b << 14) + (h0 + t) * 128 + w)) << 4);
        *(us8*)&Qpk[t * 8] = *(const us8*)p;
    } else if (t == 64) {
        us8 z = {0,0,0,0,0,0,0,0};
        *(us8*)&Qpk[64 * 8] = z;
    } else if (t >= 128 && t < 256) {
        const u16* p = qkTr + (((long)((b << 14) + (t - 128) * 128 + w)) << 4);
        *(us8*)&Kpk[(t - 128) * 8] = *(const us8*)(p + 8);
    } else if (t == 256) {
        us8 z = {0,0,0,0,0,0,0,0};
        *(us8*)&Kpk[128 * 8] = z;
    }

    const u16* vB = vTc + (((long)(b * 128 + w)) << 13);
#pragma unroll
    for (int m = t; m < 1024; m += 512) {
        int c = m >> 4, s = m & 15;
        int src = (c << 4) | (s & 8) | ((s ^ c) & 7);
        *(us8*)&Vs[m << 3] = *(const us8*)&vB[src << 3];
    }
    __syncthreads();

    int wv = t >> 6, l = t & 63;
    int m16 = l & 15, kg = l >> 4;
    f32x4 zero4 = {0.f, 0.f, 0.f, 0.f};

    // ---- QK^T: wave owns g-tile gt=wv; E[g][h0+ht*16+m16], 4 ht ----
    int gt = wv;
    bf16x8 afr;
    { int sl = (kg == 0) ? (gt * 16 + m16) : 128;
      afr = *(const bf16x8*)&Kpk[sl * 8]; }
    int kgr = ((gt & 1) << 1) | (kg >> 1);
    int jb  = (kg & 1) << 2;
    int gbase = gt * 16 + kg * 4;
#pragma unroll
    for (int ht = 0; ht < 4; ht++) {
        int slB = (kg == 0) ? (ht * 16 + m16) : 64;
        bf16x8 bfr = *(const bf16x8*)&Qpk[slB * 8];
        f32x4 e = __builtin_amdgcn_mfma_f32_16x16x32_bf16(afr, bfr, zero4, 0, 0, 0);
        u16 u0[4];
#pragma unroll
        for (int r = 0; r < 4; r++) {
            int g = gbase + r, h = h0 + ht * 16 + m16;
            float val = (g == h) ? 0.f : __expf(e[r]);
            u0[r] = f2bf(val);
        }
        int eidx = ((((ht << 2) | (gt >> 1)) * 64 + kgr * 16 + m16) << 3) + jb;
        u32x2 pk2;
        pk2.x = (unsigned)u0[0] | ((unsigned)u0[1] << 16);
        pk2.y = (unsigned)u0[2] | ((unsigned)u0[3] << 16);
        *(u32x2*)&Epk[eidx] = pk2;
    }
    __syncthreads();

    // ---- PV: wave (cp, hq): c-tiles {2cp,2cp+1}, h-tile hq ----
    int cp = wv >> 2, hq = wv & 3;
    bf16x8 bE[4];
#pragma unroll
    for (int kt = 0; kt < 4; kt++)
        bE[kt] = *(const bf16x8*)&Epk[(((hq << 2) + kt) * 64 + l) << 3];

    f32x4 acc[2];
    acc[0] = zero4; acc[1] = zero4;
#pragma unroll
    for (int ci = 0; ci < 2; ci++) {
        int ct = cp * 2 + ci;
#pragma unroll
        for (int kt = 0; kt < 4; kt++) {
            int slot = ((ct * 16 + m16) << 4) | ((((kt << 2) | kg)) ^ (m16 & 7));
            bf16x8 aV = *(const bf16x8*)&Vs[slot << 3];
            acc[ci] = __builtin_amdgcn_mfma_f32_16x16x32_bf16(aV, bE[kt], acc[ci], 0, 0, 0);
        }
    }
    f32x4 accS = zero4;
    if (cp == 0) {
        bf16x8 ones;
        short ov = (m16 == 0) ? (short)0x3F80 : (short)0;
#pragma unroll
        for (int j = 0; j < 8; j++) ones[j] = ov;
#pragma unroll
        for (int kt = 0; kt < 4; kt++)
            accS = __builtin_amdgcn_mfma_f32_16x16x32_bf16(ones, bE[kt], accS, 0, 0, 0);
    }

    int hcol = h0 + hq * 16 + m16;
    long obase = (((long)(b * 128 + w)) * 128 + hcol) * 64 + cp * 32;
#pragma unroll
    for (int ci = 0; ci < 2; ci++) {
        us4 pkd = { f2bf(acc[ci][0]), f2bf(acc[ci][1]), f2bf(acc[ci][2]), f2bf(acc[ci][3]) };
        *(us4*)&accHt[obase + ci * 16 + kg * 4] = pkd;
    }
    if (cp == 0 && kg == 0)
        sH[(b * 128 + w) * 128 + hcol] = accS[0];
}

// ---------------------------------------------------------------------------
// Kernel 4: row attention + fused finalize, w-split. Block (b, h, wh).
// ---------------------------------------------------------------------------
__global__ __launch_bounds__(512) void rowW_fin_kernel(
    const u16* __restrict__ qkTr, const u16* __restrict__ vb16,
    const u16* __restrict__ accHt, const float* __restrict__ sH,
    const float* __restrict__ x, const float* __restrict__ gamma,
    float* __restrict__ out)
{
    __shared__ u16 Qpk[65 * 8];
    __shared__ u16 Kpk[129 * 8];
    __shared__ u16 Epk[1024 * 8];   // 16 KB
    __shared__ u16 Vs[1024 * 8];    // 16 KB

    int t = threadIdx.x;
    int bid = blockIdx.x;
    int wg = ((bid & 7) << 9) | (bid >> 3);
    int b = wg >> 8, h = (wg >> 1) & 127, wh = wg & 1;
    int w0 = wh << 6;
    float gm = gamma[0];

    int wv = t >> 6, l = t & 63;
    int m16 = l & 15, kg = l >> 4;
    int cp = wv >> 2, hq = wv & 3;
    int wcol = hq * 16 + m16;          // w within half
    int wfull = w0 + wcol;

    // ---- hoisted finalize loads ----
    float sHreg = sH[((long)(b * 128 + wfull)) * 128 + h];
    us4 hA0, hA1;
    {
        long hbase = (((long)(b * 128 + wfull)) * 128 + h) * 64 + cp * 32 + (kg << 2);
        hA0 = *(const us4*)&accHt[hbase];
        hA1 = *(const us4*)&accHt[hbase + 16];
    }
    long obase = ((long)b << 20) + (h << 7) + wfull;
    float xr[2][4];
#pragma unroll
    for (int ci = 0; ci < 2; ci++)
#pragma unroll
        for (int r = 0; r < 4; r++)
            xr[ci][r] = x[obase + ((long)(cp * 32 + ci * 16 + (kg << 2) + r) << 14)];

    // ---- staging ----
    if (t < 64) {
        const u16* p = qkTr + (((long)((b << 14) + h * 128 + w0 + t)) << 4);
        *(us8*)&Qpk[t * 8] = *(const us8*)p;
    } else if (t == 64) {
        us8 z = {0,0,0,0,0,0,0,0};
        *(us8*)&Qpk[64 * 8] = z;
    } else if (t >= 128 && t < 256) {
        const u16* p = qkTr + (((long)((b << 14) + h * 128 + (t - 128))) << 4);
        *(us8*)&Kpk[(t - 128) * 8] = *(const us8*)(p + 8);
    } else if (t == 256) {
        us8 z = {0,0,0,0,0,0,0,0};
        *(us8*)&Kpk[128 * 8] = z;
    }

    const u16* vB = vb16 + ((long)b << 20) + (h << 7);
#pragma unroll
    for (int m = t; m < 1024; m += 512) {
        int c = m >> 4, s = m & 15;
        int src = (s & 8) | ((s ^ c) & 7);
        *(us8*)&Vs[m << 3] = *(const us8*)&vB[((long)c << 14) + (src << 3)];
    }

    // keep-alive pins: force the finalize loads to complete here (rule #17)
    {
        uint2 p0 = *(uint2*)&hA0, p1 = *(uint2*)&hA1;
        asm volatile("" :: "v"(sHreg), "v"(p0.x), "v"(p0.y), "v"(p1.x), "v"(p1.y));
        asm volatile("" :: "v"(xr[0][0]), "v"(xr[0][1]), "v"(xr[0][2]), "v"(xr[0][3]),
                          "v"(xr[1][0]), "v"(xr[1][1]), "v"(xr[1][2]), "v"(xr[1][3]));
    }
    __syncthreads();

    f32x4 zero4 = {0.f, 0.f, 0.f, 0.f};

    // ---- QK^T: wave owns v-tile gt=wv; E[v][w0+ht*16+m16], 4 ht, no mask ----
    int gt = wv;
    bf16x8 afr;
    { int sl = (kg == 0) ? (gt * 16 + m16) : 128;
      afr = *(const bf16x8*)&Kpk[sl * 8]; }
    int kgr = ((gt & 1) << 1) | (kg >> 1);
    int jb  = (kg & 1) << 2;
#pragma unroll
    for (int ht = 0; ht < 4; ht++) {
        int slB = (kg == 0) ? (ht * 16 + m16) : 64;
        bf16x8 bfr = *(const bf16x8*)&Qpk[slB * 8];
        f32x4 e = __builtin_amdgcn_mfma_f32_16x16x32_bf16(afr, bfr, zero4, 0, 0, 0);
        u16 u0[4];
#pragma unroll
        for (int r = 0; r < 4; r++) u0[r] = f2bf(__expf(e[r]));
        int eidx = ((((ht << 2) | (gt >> 1)) * 64 + kgr * 16 + m16) << 3) + jb;
        u32x2 pk2;
        pk2.x = (unsigned)u0[0] | ((unsigned)u0[1] << 16);
        pk2.y = (unsigned)u0[2] | ((unsigned)u0[3] << 16);
        *(u32x2*)&Epk[eidx] = pk2;
    }
    __syncthreads();

    // ---- PV: wave (cp, hq): c-tiles {2cp,2cp+1}, w-tile hq ----
    bf16x8 bE[4];
#pragma unroll
    for (int kt = 0; kt < 4; kt++)
        bE[kt] = *(const bf16x8*)&Epk[(((hq << 2) + kt) * 64 + l) << 3];

    f32x4 acc[2];
    acc[0] = zero4; acc[1] = zero4;
#pragma unroll
    for (int ci = 0; ci < 2; ci++) {
        int ct = cp * 2 + ci;
#pragma unroll
        for (int kt = 0; kt < 4; kt++) {
            int slot = ((ct * 16 + m16) << 4) | ((((kt << 2) | kg)) ^ (m16 & 7));
            bf16x8 aV = *(const bf16x8*)&Vs[slot << 3];
            acc[ci] = __builtin_amdgcn_mfma_f32_16x16x32_bf16(aV, bE[kt], acc[ci], 0, 0, 0);
        }
    }
    // ones row duplicated on BOTH cp halves so the sW shfl stays wave-local
    f32x4 accS = zero4;
    {
        bf16x8 ones;
        short ov = (m16 == 0) ? (short)0x3F80 : (short)0;
#pragma unroll
        for (int j = 0; j < 8; j++) ones[j] = ov;
#pragma unroll
        for (int kt = 0; kt < 4; kt++)
            accS = __builtin_amdgcn_mfma_f32_16x16x32_bf16(ones, bE[kt], accS, 0, 0, 0);
    }

    float sWv_ = __shfl(accS[0], m16, 64); // D[0][m16] lives in lane m16 (kg=0)
    float grv = gm / (sHreg + sWv_);

    // ---- direct-from-register epilogue: out = grv*(accW+accH) + x ----
#pragma unroll
    for (int ci = 0; ci < 2; ci++) {
        us4 hAv = (ci == 0) ? hA0 : hA1;
#pragma unroll
        for (int r = 0; r < 4; r++) {
            long ga = obase + ((long)(cp * 32 + ci * 16 + (kg << 2) + r) << 14);
            out[ga] = grv * (acc[ci][r] + bf2f(hAv[r])) + xr[ci][r];
        }
    }
}

extern "C" void kernel_launch(void* const* d_in, const int* in_sizes, int n_in,
                              void* d_out, int out_size, void* d_ws, size_t ws_size,
                              hipStream_t stream) {
    const float* x     = (const float*)d_in[0];
    const float* Wq    = (const float*)d_in[1];
    const float* bq    = (const float*)d_in[2];
    const float* Wk    = (const float*)d_in[3];
    const float* bk    = (const float*)d_in[4];
    const float* Wv    = (const float*)d_in[5];
    const float* bv    = (const float*)d_in[6];
    const float* gamma = (const float*)d_in[7];
    float* out = (float*)d_out;

    u16* vb16  = (u16*)d_ws;                 // 16,777,216 u16 (32MB)
    u16* vTc   = vb16 + 16777216;            // 16,777,216 u16 (32MB)
    u16* qkTr  = vTc + 16777216;             // 4,194,304 u16 (8MB)
    u16* accHt = qkTr + 4194304;             // 16,777,216 u16 (32MB)
    float* sH  = (float*)(accHt + 16777216); // 262,144 f32 (1MB)
    u16* Wpk   = (u16*)(sH + 262144);        // 5,120 u16
    float* biasf = (float*)(Wpk + 5120);     // 80 f32

    wprep_kernel<<<1, 256, 0, stream>>>(Wq, bq, Wk, bk, Wv, bv, Wpk, biasf);
    proj_kernel<<<2048, 256, 0, stream>>>(x, Wpk, biasf, vb16, qkTr);
    vtrans_kernel<<<16384, 256, 0, stream>>>(vb16, vTc);
    colH_kernel<<<4096, 512, 0, stream>>>(qkTr, vTc, accHt, sH);
    rowW_fin_kernel<<<4096, 512, 0, stream>>>(qkTr, vb16, accHt, sH, x, gamma, out);
}

// Round 12
// 101.181 us; speedup vs baseline: 1.1485x; 1.0294x over previous
//
#include <hip/hip_runtime.h>
#include <hip/hip_bf16.h>

// B=16, C=64, CQ=8, H=W=128
typedef unsigned short u16;
typedef __attribute__((ext_vector_type(8))) short    bf16x8;
typedef __attribute__((ext_vector_type(8))) unsigned short us8;
typedef __attribute__((ext_vector_type(4))) unsigned short us4;
typedef __attribute__((ext_vector_type(4))) float    f32x4;
typedef __attribute__((ext_vector_type(2))) unsigned int u32x2;

__device__ __forceinline__ u16 f2bf(float f) {
    unsigned u = __float_as_uint(f);
    return (u16)((u + 0x7FFFu + ((u >> 16) & 1u)) >> 16);
}
__device__ __forceinline__ float bf2f(u16 v) {
    return __uint_as_float((unsigned)v << 16);
}

// ---------------------------------------------------------------------------
// Kernel 0: W prep. Packs Wv/Wq/Wk into bf16 B-frag slots
// Wpk[nt(5)][kt(2)][lane(64)][8]; biasf[80] = {bv, bq, bk}.
// ---------------------------------------------------------------------------
__global__ __launch_bounds__(256) void wprep_kernel(
    const float* __restrict__ Wq, const float* __restrict__ bq,
    const float* __restrict__ Wk, const float* __restrict__ bk,
    const float* __restrict__ Wv, const float* __restrict__ bv,
    u16* __restrict__ Wpk, float* __restrict__ biasf)
{
    int t = threadIdx.x;
    for (int s = t; s < 640; s += 256) {
        int nt = s >> 7;
        int kt = (s >> 6) & 1;
        int l  = s & 63;
        int n  = (nt << 4) | (l & 15);
        int k0 = kt * 32 + ((l >> 4) << 3);
        const float* row;
        if (n < 64) row = Wv + n * 64;
        else if (n < 72) row = Wq + (n - 64) * 64;
        else row = Wk + (n - 72) * 64;
        us8 o;
#pragma unroll
        for (int j = 0; j < 8; j++) o[j] = f2bf(row[k0 + j]);
        *(us8*)&Wpk[s * 8] = o;
    }
    if (t < 80) {
        float bb;
        if (t < 64) bb = bv[t];
        else if (t < 72) bb = bq[t - 64];
        else bb = bk[t - 72];
        biasf[t] = bb;
    }
}

// ---------------------------------------------------------------------------
// Kernel 1: projections via MFMA — streaming input, LDS-staged v output.
// Block = 128 pixels (one h row), 256 thr = 4 waves.
// v output staged in XOR-swizzled LDS -> linear us8 stores (4x256B segs/instr).
// ---------------------------------------------------------------------------
__global__ __launch_bounds__(256) void proj_kernel(
    const float* __restrict__ x, const u16* __restrict__ Wpk,
    const float* __restrict__ biasf,
    u16* __restrict__ vb16, u16* __restrict__ qkTr)
{
    __shared__ u16 qstage[4][32 * 16];   // 4 KB
    __shared__ u16 Ld16[64 * 128];       // 16 KB v-stage

    int t = threadIdx.x;
    int bid = blockIdx.x;
    int wg = ((bid & 7) << 8) | (bid >> 3);   // b-matched XCD swizzle
    int b = wg >> 7;
    int hw0 = (wg & 127) << 7;                // one h-row (128 w)
    const float* xb = x + ((long)b << 20) + hw0;

    int wv = t >> 6, l = t & 63;
    int m16 = l & 15, kg = l >> 4;
    int pixb = wv << 5;

    // ---- A-frags direct from global ----
    bf16x8 af[2][2];
#pragma unroll
    for (int mt = 0; mt < 2; mt++) {
        int pix = pixb + (mt << 4) + m16;
#pragma unroll
        for (int kt = 0; kt < 2; kt++) {
            float v[8];
#pragma unroll
            for (int j = 0; j < 8; j++)
                v[j] = xb[((kt * 32 + (kg << 3) + j) << 14) + pix];
            us8 a;
#pragma unroll
            for (int j = 0; j < 8; j++) a[j] = f2bf(v[j]);
            af[mt][kt] = (bf16x8)a;
        }
    }

    f32x4 acc[2][5];
#pragma unroll
    for (int nt = 0; nt < 5; nt++) {
        float bb = biasf[(nt << 4) + m16];
        f32x4 binit = {bb, bb, bb, bb};
        bf16x8 b0 = *(const bf16x8*)&Wpk[(((nt << 1) + 0) << 9) + (l << 3)];
        bf16x8 b1 = *(const bf16x8*)&Wpk[(((nt << 1) + 1) << 9) + (l << 3)];
#pragma unroll
        for (int mt = 0; mt < 2; mt++) {
            f32x4 a_ = binit;
            a_ = __builtin_amdgcn_mfma_f32_16x16x32_bf16(af[mt][0], b0, a_, 0, 0, 0);
            a_ = __builtin_amdgcn_mfma_f32_16x16x32_bf16(af[mt][1], b1, a_, 0, 0, 0);
            acc[mt][nt] = a_;
        }
    }

    // ---- v -> LDS stage (XOR-swizzled; 2-way max, free) ----
#pragma unroll
    for (int mt = 0; mt < 2; mt++) {
        int pixq = pixb + (mt << 4) + (kg << 2);
#pragma unroll
        for (int nt = 0; nt < 4; nt++) {
            int c = (nt << 4) + m16;
            us4 pkd = { f2bf(acc[mt][nt][0]), f2bf(acc[mt][nt][1]),
                        f2bf(acc[mt][nt][2]), f2bf(acc[mt][nt][3]) };
            int byte = (c << 8) + (pixq << 1);
            byte ^= (c & 7) << 4;
            *(us4*)((char*)Ld16 + byte) = pkd;
        }
    }

    // ---- qk store: wave-local LDS transpose -> coalesced us8 store ----
    {
        u16* qs = qstage[wv];
#pragma unroll
        for (int mt = 0; mt < 2; mt++) {
#pragma unroll
            for (int r = 0; r < 4; r++)
                qs[((mt << 4) + (kg << 2) + r) * 16 + m16] = f2bf(acc[mt][4][r]);
        }
        int pixl = l >> 1, half = l & 1;
        us8 o = *(us8*)&qs[pixl * 16 + half * 8];
        *(us8*)&qkTr[(((long)((b << 14) + hw0 + pixb + pixl)) << 4) + half * 8] = o;
    }
    __syncthreads();

    // ---- linear v stores: 4 us8/thread, 4x256B segments per instr ----
    long vb2 = ((long)b << 20) + hw0;
#pragma unroll
    for (int u = 0; u < 4; u++) {
        int lin = (u << 12) + (t << 4);        // byte index in Ld16
        int c = lin >> 8;
        int srcb = (c << 8) + ((((lin >> 4) & 15) << 4) ^ ((c & 7) << 4));
        us8 vv = *(const us8*)((char*)Ld16 + srcb);
        *(us8*)&vb16[vb2 + (c << 14) + ((t & 15) << 3)] = vv;
    }
}

// ---------------------------------------------------------------------------
// Kernel 2: v transpose: vb16[b][c][g][w] -> vTc[b][w][c][g] (bf16).
// ---------------------------------------------------------------------------
__global__ __launch_bounds__(256) void vtrans_kernel(
    const u16* __restrict__ vb16, u16* __restrict__ vTc)
{
    __shared__ u16 tile[32][33];
    int t = threadIdx.x;
    int bid = blockIdx.x;
    int vwg = ((bid & 7) << 11) | (bid >> 3);  // b-matched XCD swizzle
    int b = vwg >> 10;
    int c = (vwg >> 4) & 63;
    int g0 = ((vwg >> 2) & 3) * 32, w0 = (vwg & 3) * 32;
    const u16* src = vb16 + ((b * 64 + c) << 14);
#pragma unroll
    for (int it = 0; it < 4; it++) {
        int i = it * 8 + (t >> 5), j = t & 31;
        tile[i][j] = src[(g0 + i) * 128 + w0 + j];
    }
    __syncthreads();
    int j = t >> 3, i4 = (t & 7) * 4;
    us4 o = { tile[i4][j], tile[i4 + 1][j], tile[i4 + 2][j], tile[i4 + 3][j] };
    *(us4*)&vTc[((b * 128 + w0 + j) * 64 + c) * 128 + g0 + i4] = o;
}

// ---------------------------------------------------------------------------
// Kernel 3: column attention, h-split. Block (b, w, hh); 4096 blocks.
// Epilogue: wave shfl-repack -> one us8 store per lane (16x64B segments).
// ---------------------------------------------------------------------------
__global__ __launch_bounds__(512) void colH_kernel(
    const u16* __restrict__ qkTr, const u16* __restrict__ vTc,
    u16* __restrict__ accHt, float* __restrict__ sH)
{
    __shared__ u16 Qpk[65 * 8];        // h-half Q + zero slot 64
    __shared__ u16 Kpk[129 * 8];       // full column K + zero slot 128
    __shared__ u16 Epk[1024 * 8];      // 16 KB
    __shared__ u16 Vs[1024 * 8];       // 16 KB

    int t = threadIdx.x;
    int bid = blockIdx.x;
    int wg = ((bid & 7) << 9) | (bid >> 3);   // bijective, b-contiguous per XCD
    int b = wg >> 8, w = (wg >> 1) & 127, hh = wg & 1;
    int h0 = hh << 6;

    if (t < 64) {
        const u16* p = qkTr + (((long)((b << 14) + (h0 + t) * 128 + w)) << 4);
        *(us8*)&Qpk[t * 8] = *(const us8*)p;
    } else if (t == 64) {
        us8 z = {0,0,0,0,0,0,0,0};
        *(us8*)&Qpk[64 * 8] = z;
    } else if (t >= 128 && t < 256) {
        const u16* p = qkTr + (((long)((b << 14) + (t - 128) * 128 + w)) << 4);
        *(us8*)&Kpk[(t - 128) * 8] = *(const us8*)(p + 8);
    } else if (t == 256) {
        us8 z = {0,0,0,0,0,0,0,0};
        *(us8*)&Kpk[128 * 8] = z;
    }

    const u16* vB = vTc + (((long)(b * 128 + w)) << 13);
#pragma unroll
    for (int m = t; m < 1024; m += 512) {
        int c = m >> 4, s = m & 15;
        int src = (c << 4) | (s & 8) | ((s ^ c) & 7);
        *(us8*)&Vs[m << 3] = *(const us8*)&vB[src << 3];
    }
    __syncthreads();

    int wv = t >> 6, l = t & 63;
    int m16 = l & 15, kg = l >> 4;
    f32x4 zero4 = {0.f, 0.f, 0.f, 0.f};

    // ---- QK^T: wave owns g-tile gt=wv; E[g][h0+ht*16+m16], 4 ht ----
    int gt = wv;
    bf16x8 afr;
    { int sl = (kg == 0) ? (gt * 16 + m16) : 128;
      afr = *(const bf16x8*)&Kpk[sl * 8]; }
    int kgr = ((gt & 1) << 1) | (kg >> 1);
    int jb  = (kg & 1) << 2;
    int gbase = gt * 16 + kg * 4;
#pragma unroll
    for (int ht = 0; ht < 4; ht++) {
        int slB = (kg == 0) ? (ht * 16 + m16) : 64;
        bf16x8 bfr = *(const bf16x8*)&Qpk[slB * 8];
        f32x4 e = __builtin_amdgcn_mfma_f32_16x16x32_bf16(afr, bfr, zero4, 0, 0, 0);
        u16 u0[4];
#pragma unroll
        for (int r = 0; r < 4; r++) {
            int g = gbase + r, h = h0 + ht * 16 + m16;
            float val = (g == h) ? 0.f : __expf(e[r]);
            u0[r] = f2bf(val);
        }
        int eidx = ((((ht << 2) | (gt >> 1)) * 64 + kgr * 16 + m16) << 3) + jb;
        u32x2 pk2;
        pk2.x = (unsigned)u0[0] | ((unsigned)u0[1] << 16);
        pk2.y = (unsigned)u0[2] | ((unsigned)u0[3] << 16);
        *(u32x2*)&Epk[eidx] = pk2;
    }
    __syncthreads();

    // ---- PV: wave (cp, hq): c-tiles {2cp,2cp+1}, h-tile hq ----
    int cp = wv >> 2, hq = wv & 3;
    bf16x8 bE[4];
#pragma unroll
    for (int kt = 0; kt < 4; kt++)
        bE[kt] = *(const bf16x8*)&Epk[(((hq << 2) + kt) * 64 + l) << 3];

    f32x4 acc[2];
    acc[0] = zero4; acc[1] = zero4;
#pragma unroll
    for (int ci = 0; ci < 2; ci++) {
        int ct = cp * 2 + ci;
#pragma unroll
        for (int kt = 0; kt < 4; kt++) {
            int slot = ((ct * 16 + m16) << 4) | ((((kt << 2) | kg)) ^ (m16 & 7));
            bf16x8 aV = *(const bf16x8*)&Vs[slot << 3];
            acc[ci] = __builtin_amdgcn_mfma_f32_16x16x32_bf16(aV, bE[kt], acc[ci], 0, 0, 0);
        }
    }
    f32x4 accS = zero4;
    if (cp == 0) {
        bf16x8 ones;
        short ov = (m16 == 0) ? (short)0x3F80 : (short)0;
#pragma unroll
        for (int j = 0; j < 8; j++) ones[j] = ov;
#pragma unroll
        for (int kt = 0; kt < 4; kt++)
            accS = __builtin_amdgcn_mfma_f32_16x16x32_bf16(ones, bE[kt], accS, 0, 0, 0);
    }

    // ---- epilogue: shfl-repack -> one us8 store per lane ----
    u32x2 pk[2];
#pragma unroll
    for (int ci = 0; ci < 2; ci++) {
        pk[ci].x = (unsigned)f2bf(acc[ci][0]) | ((unsigned)f2bf(acc[ci][1]) << 16);
        pk[ci].y = (unsigned)f2bf(acc[ci][2]) | ((unsigned)f2bf(acc[ci][3]) << 16);
    }
    int q = l & 3, hrow = l >> 2;
    int sA = ((q & 1) << 5) | hrow;       // src lane kg=2*(q&1), m16=hrow
    int sB = sA + 16;                     // kg+1
    unsigned a0 = __shfl(pk[0].x, sA, 64), a1 = __shfl(pk[0].y, sA, 64);
    unsigned a2 = __shfl(pk[1].x, sA, 64), a3 = __shfl(pk[1].y, sA, 64);
    unsigned b0 = __shfl(pk[0].x, sB, 64), b1 = __shfl(pk[0].y, sB, 64);
    unsigned b2 = __shfl(pk[1].x, sB, 64), b3 = __shfl(pk[1].y, sB, 64);
    int cisel = q >> 1;
    uint4 o;
    o.x = cisel ? a2 : a0;  o.y = cisel ? a3 : a1;
    o.z = cisel ? b2 : b0;  o.w = cisel ? b3 : b1;
    long oaddr = (((long)(b * 128 + w)) * 128 + h0 + hq * 16 + hrow) * 64
               + cp * 32 + q * 8;
    *(uint4*)&accHt[oaddr] = o;

    if (cp == 0 && kg == 0)
        sH[(b * 128 + w) * 128 + h0 + hq * 16 + m16] = accS[0];
}

// ---------------------------------------------------------------------------
// Kernel 4: row attention + fused finalize, w-split. Block (b, h, wh).
// accHt read: ONE coalesced us8 per lane (pinned at start), shfl-
// redistributed after PV. Direct-from-register epilogue.
// ---------------------------------------------------------------------------
__global__ __launch_bounds__(512) void rowW_fin_kernel(
    const u16* __restrict__ qkTr, const u16* __restrict__ vb16,
    const u16* __restrict__ accHt, const float* __restrict__ sH,
    const float* __restrict__ x, const float* __restrict__ gamma,
    float* __restrict__ out)
{
    __shared__ u16 Qpk[65 * 8];
    __shared__ u16 Kpk[129 * 8];
    __shared__ u16 Epk[1024 * 8];   // 16 KB
    __shared__ u16 Vs[1024 * 8];    // 16 KB

    int t = threadIdx.x;
    int bid = blockIdx.x;
    int wg = ((bid & 7) << 9) | (bid >> 3);
    int b = wg >> 8, h = (wg >> 1) & 127, wh = wg & 1;
    int w0 = wh << 6;
    float gm = gamma[0];

    int wv = t >> 6, l = t & 63;
    int m16 = l & 15, kg = l >> 4;
    int cp = wv >> 2, hq = wv & 3;
    int wcol = hq * 16 + m16;          // w within half
    int wfull = w0 + wcol;

    // ---- hoisted finalize loads ----
    float sHreg = sH[((long)(b * 128 + wfull)) * 128 + h];
    // coalesced accHt: lane j covers w = w0+hq*16+(j>>2), c-oct cp*4+(j&3)
    uint4 hAw;
    {
        long hb = (((long)(b * 128 + w0 + (hq << 4) + (l >> 2))) * 128 + h) * 64
                + cp * 32 + ((l & 3) << 3);
        hAw = *(const uint4*)&accHt[hb];
    }
    long obase = ((long)b << 20) + (h << 7) + wfull;
    float xr[2][4];
#pragma unroll
    for (int ci = 0; ci < 2; ci++)
#pragma unroll
        for (int r = 0; r < 4; r++)
            xr[ci][r] = x[obase + ((long)(cp * 32 + ci * 16 + (kg << 2) + r) << 14)];

    // ---- staging ----
    if (t < 64) {
        const u16* p = qkTr + (((long)((b << 14) + h * 128 + w0 + t)) << 4);
        *(us8*)&Qpk[t * 8] = *(const us8*)p;
    } else if (t == 64) {
        us8 z = {0,0,0,0,0,0,0,0};
        *(us8*)&Qpk[64 * 8] = z;
    } else if (t >= 128 && t < 256) {
        const u16* p = qkTr + (((long)((b << 14) + h * 128 + (t - 128))) << 4);
        *(us8*)&Kpk[(t - 128) * 8] = *(const us8*)(p + 8);
    } else if (t == 256) {
        us8 z = {0,0,0,0,0,0,0,0};
        *(us8*)&Kpk[128 * 8] = z;
    }

    const u16* vB = vb16 + ((long)b << 20) + (h << 7);
#pragma unroll
    for (int m = t; m < 1024; m += 512) {
        int c = m >> 4, s = m & 15;
        int src = (s & 8) | ((s ^ c) & 7);
        *(us8*)&Vs[m << 3] = *(const us8*)&vB[((long)c << 14) + (src << 3)];
    }

    // keep-alive pins (rule #17)
    {
        asm volatile("" :: "v"(sHreg), "v"(hAw.x), "v"(hAw.y), "v"(hAw.z), "v"(hAw.w));
        asm volatile("" :: "v"(xr[0][0]), "v"(xr[0][1]), "v"(xr[0][2]), "v"(xr[0][3]),
                          "v"(xr[1][0]), "v"(xr[1][1]), "v"(xr[1][2]), "v"(xr[1][3]));
    }
    __syncthreads();

    f32x4 zero4 = {0.f, 0.f, 0.f, 0.f};

    // ---- QK^T: wave owns v-tile gt=wv; E[v][w0+ht*16+m16], 4 ht, no mask ----
    int gt = wv;
    bf16x8 afr;
    { int sl = (kg == 0) ? (gt * 16 + m16) : 128;
      afr = *(const bf16x8*)&Kpk[sl * 8]; }
    int kgr = ((gt & 1) << 1) | (kg >> 1);
    int jb  = (kg & 1) << 2;
#pragma unroll
    for (int ht = 0; ht < 4; ht++) {
        int slB = (kg == 0) ? (ht * 16 + m16) : 64;
        bf16x8 bfr = *(const bf16x8*)&Qpk[slB * 8];
        f32x4 e = __builtin_amdgcn_mfma_f32_16x16x32_bf16(afr, bfr, zero4, 0, 0, 0);
        u16 u0[4];
#pragma unroll
        for (int r = 0; r < 4; r++) u0[r] = f2bf(__expf(e[r]));
        int eidx = ((((ht << 2) | (gt >> 1)) * 64 + kgr * 16 + m16) << 3) + jb;
        u32x2 pk2;
        pk2.x = (unsigned)u0[0] | ((unsigned)u0[1] << 16);
        pk2.y = (unsigned)u0[2] | ((unsigned)u0[3] << 16);
        *(u32x2*)&Epk[eidx] = pk2;
    }
    __syncthreads();

    // ---- PV: wave (cp, hq): c-tiles {2cp,2cp+1}, w-tile hq ----
    bf16x8 bE[4];
#pragma unroll
    for (int kt = 0; kt < 4; kt++)
        bE[kt] = *(const bf16x8*)&Epk[(((hq << 2) + kt) * 64 + l) << 3];

    f32x4 acc[2];
    acc[0] = zero4; acc[1] = zero4;
#pragma unroll
    for (int ci = 0; ci < 2; ci++) {
        int ct = cp * 2 + ci;
#pragma unroll
        for (int kt = 0; kt < 4; kt++) {
            int slot = ((ct * 16 + m16) << 4) | ((((kt << 2) | kg)) ^ (m16 & 7));
            bf16x8 aV = *(const bf16x8*)&Vs[slot << 3];
            acc[ci] = __builtin_amdgcn_mfma_f32_16x16x32_bf16(aV, bE[kt], acc[ci], 0, 0, 0);
        }
    }
    // ones row duplicated on BOTH cp halves so the sW shfl stays wave-local
    f32x4 accS = zero4;
    {
        bf16x8 ones;
        short ov = (m16 == 0) ? (short)0x3F80 : (short)0;
#pragma unroll
        for (int j = 0; j < 8; j++) ones[j] = ov;
#pragma unroll
        for (int kt = 0; kt < 4; kt++)
            accS = __builtin_amdgcn_mfma_f32_16x16x32_bf16(ones, bE[kt], accS, 0, 0, 0);
    }

    float sWv_ = __shfl(accS[0], m16, 64); // D[0][m16] lives in lane m16 (kg=0)
    float grv = gm / (sHreg + sWv_);

    // ---- redistribute accHt to (m16,kg) layout via shfls ----
    us4 hA[2];
#pragma unroll
    for (int ci = 0; ci < 2; ci++) {
        int s = (m16 << 2) | ((ci << 1) | (kg >> 1));
        unsigned t0 = __shfl(hAw.x, s, 64), t1 = __shfl(hAw.y, s, 64);
        unsigned t2 = __shfl(hAw.z, s, 64), t3 = __shfl(hAw.w, s, 64);
        unsigned wA = (kg & 1) ? t2 : t0;
        unsigned wB = (kg & 1) ? t3 : t1;
        uint2 uu2;
        uu2.x = wA; uu2.y = wB;
        hA[ci] = *(us4*)&uu2;
    }

    // ---- direct-from-register epilogue: out = grv*(accW+accH) + x ----
#pragma unroll
    for (int ci = 0; ci < 2; ci++) {
#pragma unroll
        for (int r = 0; r < 4; r++) {
            long ga = obase + ((long)(cp * 32 + ci * 16 + (kg << 2) + r) << 14);
            out[ga] = grv * (acc[ci][r] + bf2f(hA[ci][r])) + xr[ci][r];
        }
    }
}

extern "C" void kernel_launch(void* const* d_in, const int* in_sizes, int n_in,
                              void* d_out, int out_size, void* d_ws, size_t ws_size,
                              hipStream_t stream) {
    const float* x     = (const float*)d_in[0];
    const float* Wq    = (const float*)d_in[1];
    const float* bq    = (const float*)d_in[2];
    const float* Wk    = (const float*)d_in[3];
    const float* bk    = (const float*)d_in[4];
    const float* Wv    = (const float*)d_in[5];
    const float* bv    = (const float*)d_in[6];
    const float* gamma = (const float*)d_in[7];
    float* out = (float*)d_out;

    u16* vb16  = (u16*)d_ws;                 // 16,777,216 u16 (32MB)
    u16* vTc   = vb16 + 16777216;            // 16,777,216 u16 (32MB)
    u16* qkTr  = vTc + 16777216;             // 4,194,304 u16 (8MB)
    u16* accHt = qkTr + 4194304;             // 16,777,216 u16 (32MB)
    float* sH  = (float*)(accHt + 16777216); // 262,144 f32 (1MB)
    u16* Wpk   = (u16*)(sH + 262144);        // 5,120 u16
    float* biasf = (float*)(Wpk + 5120);     // 80 f32

    wprep_kernel<<<1, 256, 0, stream>>>(Wq, bq, Wk, bk, Wv, bv, Wpk, biasf);
    proj_kernel<<<2048, 256, 0, stream>>>(x, Wpk, biasf, vb16, qkTr);
    vtrans_kernel<<<16384, 256, 0, stream>>>(vb16, vTc);
    colH_kernel<<<4096, 512, 0, stream>>>(qkTr, vTc, accHt, sH);
    rowW_fin_kernel<<<4096, 512, 0, stream>>>(qkTr, vb16, accHt, sH, x, gamma, out);
}

// Round 13
// 95.134 us; speedup vs baseline: 1.2215x; 1.0636x over previous
//
#include <hip/hip_runtime.h>
#include <hip/hip_bf16.h>

// B=16, C=64, CQ=8, H=W=128
typedef unsigned short u16;
typedef unsigned int u32;
typedef __attribute__((ext_vector_type(8))) short    bf16x8;
typedef __attribute__((ext_vector_type(8))) unsigned short us8;
typedef __attribute__((ext_vector_type(4))) unsigned short us4;
typedef __attribute__((ext_vector_type(4))) float    f32x4;
typedef __attribute__((ext_vector_type(2))) unsigned int u32x2;

__device__ __forceinline__ u16 f2bf(float f) {
    unsigned u = __float_as_uint(f);
    return (u16)((u + 0x7FFFu + ((u >> 16) & 1u)) >> 16);
}
__device__ __forceinline__ float bf2f(u16 v) {
    return __uint_as_float((unsigned)v << 16);
}

// ---------------------------------------------------------------------------
// Kernel 0: W prep. Packs Wv/Wq/Wk into bf16 B-frag slots
// Wpk[nt(5)][kt(2)][lane(64)][8]; biasf[80] = {bv, bq, bk}.
// ---------------------------------------------------------------------------
__global__ __launch_bounds__(256) void wprep_kernel(
    const float* __restrict__ Wq, const float* __restrict__ bq,
    const float* __restrict__ Wk, const float* __restrict__ bk,
    const float* __restrict__ Wv, const float* __restrict__ bv,
    u16* __restrict__ Wpk, float* __restrict__ biasf)
{
    int t = threadIdx.x;
    for (int s = t; s < 640; s += 256) {
        int nt = s >> 7;
        int kt = (s >> 6) & 1;
        int l  = s & 63;
        int n  = (nt << 4) | (l & 15);
        int k0 = kt * 32 + ((l >> 4) << 3);
        const float* row;
        if (n < 64) row = Wv + n * 64;
        else if (n < 72) row = Wq + (n - 64) * 64;
        else row = Wk + (n - 72) * 64;
        us8 o;
#pragma unroll
        for (int j = 0; j < 8; j++) o[j] = f2bf(row[k0 + j]);
        *(us8*)&Wpk[s * 8] = o;
    }
    if (t < 80) {
        float bb;
        if (t < 64) bb = bv[t];
        else if (t < 72) bb = bq[t - 64];
        else bb = bk[t - 72];
        biasf[t] = bb;
    }
}

// ---------------------------------------------------------------------------
// Kernel 1: projections via MFMA, 16h x 16w tile, 2 passes of 8 h-rows.
// Emits vb16[b][c][h][w], qkTr[b][h][w][16], AND vTc2[b][oct][w][c][g8]
// (the V^T layout colH needs) — vtrans kernel deleted.
// vstage LDS: [oct2][w16][c64(+pad)][g8], c-row stride 1040B (4-way max).
// ---------------------------------------------------------------------------
__global__ __launch_bounds__(256) void proj_kernel(
    const float* __restrict__ x, const u16* __restrict__ Wpk,
    const float* __restrict__ biasf,
    u16* __restrict__ vb16, u16* __restrict__ vTc2, u16* __restrict__ qkTr)
{
    __shared__ u16 vstage[2 * 16 * 65 * 8];   // 33.3 KB
    __shared__ u16 qstage[4][32 * 16];        // 4 KB

    int t = threadIdx.x;
    int bid = blockIdx.x;
    int wg = ((bid & 7) << 7) | (bid >> 3);   // b-matched XCD swizzle (1024=8*128)
    int b = wg >> 6;
    int hg = (wg >> 3) & 7;
    int wq = wg & 7;
    int h0 = hg << 4, w0 = wq << 4;
    const float* xb = x + ((long)b << 20);

    int wv = t >> 6, l = t & 63;
    int m16 = l & 15, kg = l >> 4;

#pragma unroll
    for (int p = 0; p < 2; p++) {
        // ---- A-frags direct from global: tile t_m = wv*2+mt (h-row) ----
        bf16x8 af[2][2];
#pragma unroll
        for (int mt = 0; mt < 2; mt++) {
            int hgl = h0 + p * 8 + wv * 2 + mt;
            int base = (hgl << 7) + w0 + m16;
#pragma unroll
            for (int kt = 0; kt < 2; kt++) {
                float v[8];
#pragma unroll
                for (int j = 0; j < 8; j++)
                    v[j] = xb[((kt * 32 + (kg << 3) + j) << 14) + base];
                us8 a;
#pragma unroll
                for (int j = 0; j < 8; j++) a[j] = f2bf(v[j]);
                af[mt][kt] = (bf16x8)a;
            }
        }

        f32x4 acc[2][5];
#pragma unroll
        for (int nt = 0; nt < 5; nt++) {
            float bb = biasf[(nt << 4) + m16];
            f32x4 binit = {bb, bb, bb, bb};
            bf16x8 b0 = *(const bf16x8*)&Wpk[(((nt << 1) + 0) << 9) + (l << 3)];
            bf16x8 b1 = *(const bf16x8*)&Wpk[(((nt << 1) + 1) << 9) + (l << 3)];
#pragma unroll
            for (int mt = 0; mt < 2; mt++) {
                f32x4 a_ = binit;
                a_ = __builtin_amdgcn_mfma_f32_16x16x32_bf16(af[mt][0], b0, a_, 0, 0, 0);
                a_ = __builtin_amdgcn_mfma_f32_16x16x32_bf16(af[mt][1], b1, a_, 0, 0, 0);
                acc[mt][nt] = a_;
            }
        }

        // ---- vb16 stores: us4 (4 w), 16x32B segments per instr ----
#pragma unroll
        for (int mt = 0; mt < 2; mt++) {
            int hgl = h0 + p * 8 + wv * 2 + mt;
            long vbase = ((long)b << 20) + (hgl << 7) + w0 + (kg << 2);
#pragma unroll
            for (int nt = 0; nt < 4; nt++) {
                int c = (nt << 4) + m16;
                us4 pkd = { f2bf(acc[mt][nt][0]), f2bf(acc[mt][nt][1]),
                            f2bf(acc[mt][nt][2]), f2bf(acc[mt][nt][3]) };
                *(us4*)&vb16[vbase + (c << 14)] = pkd;
            }
        }

        // ---- vstage writes: u32 = {g=wv*2 (mt0), g=wv*2+1 (mt1)} ----
#pragma unroll
        for (int nt = 0; nt < 4; nt++) {
#pragma unroll
            for (int r = 0; r < 4; r++) {
                int c = (nt << 4) + m16;
                int wl = (kg << 2) + r;
                u32 pkv = (u32)f2bf(acc[0][nt][r]) | ((u32)f2bf(acc[1][nt][r]) << 16);
                *(u32*)((char*)vstage + p * 16640 + wl * 1040 + c * 16 + wv * 4) = pkv;
            }
        }

        // ---- qk: wave-local LDS transpose -> 2x512B stores ----
        {
            u16* qs = qstage[wv];
#pragma unroll
            for (int mt = 0; mt < 2; mt++) {
#pragma unroll
                for (int r = 0; r < 4; r++)
                    qs[((mt << 4) + (kg << 2) + r) * 16 + m16] = f2bf(acc[mt][4][r]);
            }
            int pixl = l >> 1, half = l & 1;
            us8 o = *(us8*)&qs[pixl * 16 + half * 8];
            int hgl = h0 + p * 8 + wv * 2 + (pixl >> 4);
            int wgl = w0 + (pixl & 15);
            *(us8*)&qkTr[(((long)((b << 14) + hgl * 128 + wgl)) << 4) + half * 8] = o;
        }
    }
    __syncthreads();

    // ---- vTc2 write-out: 8 iters, 1KB contiguous per wave-instr ----
#pragma unroll
    for (int u = 0; u < 8; u++) {
        int lin = (u << 8) + t;           // [p][wl][c]
        int c = lin & 63, wl = (lin >> 6) & 15, p = lin >> 10;
        us8 vv = *(const us8*)((char*)vstage + p * 16640 + wl * 1040 + c * 16);
        long dst = ((((long)(b * 16 + hg * 2 + p)) * 128 + w0 + wl) * 64 + c) << 3;
        *(us8*)&vTc2[dst] = vv;
    }
}

// ---------------------------------------------------------------------------
// Kernel 3: column attention, h-split. Block (b, w, hh); 4096 blocks.
// V staged from vTc2[b][oct][w][c][g8]; same slot algebra as before.
// ---------------------------------------------------------------------------
__global__ __launch_bounds__(512) void colH_kernel(
    const u16* __restrict__ qkTr, const u16* __restrict__ vTc2,
    u16* __restrict__ accHt, float* __restrict__ sH)
{
    __shared__ u16 Qpk[65 * 8];        // h-half Q + zero slot 64
    __shared__ u16 Kpk[129 * 8];       // full column K + zero slot 128
    __shared__ u16 Epk[1024 * 8];      // 16 KB
    __shared__ u16 Vs[1024 * 8];       // 16 KB

    int t = threadIdx.x;
    int bid = blockIdx.x;
    int wg = ((bid & 7) << 9) | (bid >> 3);   // bijective, b-contiguous per XCD
    int b = wg >> 8, w = (wg >> 1) & 127, hh = wg & 1;
    int h0 = hh << 6;

    if (t < 64) {
        const u16* p = qkTr + (((long)((b << 14) + (h0 + t) * 128 + w)) << 4);
        *(us8*)&Qpk[t * 8] = *(const us8*)p;
    } else if (t == 64) {
        us8 z = {0,0,0,0,0,0,0,0};
        *(us8*)&Qpk[64 * 8] = z;
    } else if (t >= 128 && t < 256) {
        const u16* p = qkTr + (((long)((b << 14) + (t - 128) * 128 + w)) << 4);
        *(us8*)&Kpk[(t - 128) * 8] = *(const us8*)(p + 8);
    } else if (t == 256) {
        us8 z = {0,0,0,0,0,0,0,0};
        *(us8*)&Kpk[128 * 8] = z;
    }

#pragma unroll
    for (int m = t; m < 1024; m += 512) {
        int c = m >> 4, s = m & 15;
        int oct = (s & 8) | ((s ^ c) & 7);
        const u16* srcp = vTc2 + ((((long)(b * 16 + oct)) * 128 + w) * 64 + c) * 8;
        *(us8*)&Vs[m << 3] = *(const us8*)srcp;
    }
    __syncthreads();

    int wv = t >> 6, l = t & 63;
    int m16 = l & 15, kg = l >> 4;
    f32x4 zero4 = {0.f, 0.f, 0.f, 0.f};

    // ---- QK^T: wave owns g-tile gt=wv; E[g][h0+ht*16+m16], 4 ht ----
    int gt = wv;
    bf16x8 afr;
    { int sl = (kg == 0) ? (gt * 16 + m16) : 128;
      afr = *(const bf16x8*)&Kpk[sl * 8]; }
    int kgr = ((gt & 1) << 1) | (kg >> 1);
    int jb  = (kg & 1) << 2;
    int gbase = gt * 16 + kg * 4;
#pragma unroll
    for (int ht = 0; ht < 4; ht++) {
        int slB = (kg == 0) ? (ht * 16 + m16) : 64;
        bf16x8 bfr = *(const bf16x8*)&Qpk[slB * 8];
        f32x4 e = __builtin_amdgcn_mfma_f32_16x16x32_bf16(afr, bfr, zero4, 0, 0, 0);
        u16 u0[4];
#pragma unroll
        for (int r = 0; r < 4; r++) {
            int g = gbase + r, h = h0 + ht * 16 + m16;
            float val = (g == h) ? 0.f : __expf(e[r]);
            u0[r] = f2bf(val);
        }
        int eidx = ((((ht << 2) | (gt >> 1)) * 64 + kgr * 16 + m16) << 3) + jb;
        u32x2 pk2;
        pk2.x = (unsigned)u0[0] | ((unsigned)u0[1] << 16);
        pk2.y = (unsigned)u0[2] | ((unsigned)u0[3] << 16);
        *(u32x2*)&Epk[eidx] = pk2;
    }
    __syncthreads();

    // ---- PV: wave (cp, hq): c-tiles {2cp,2cp+1}, h-tile hq ----
    int cp = wv >> 2, hq = wv & 3;
    bf16x8 bE[4];
#pragma unroll
    for (int kt = 0; kt < 4; kt++)
        bE[kt] = *(const bf16x8*)&Epk[(((hq << 2) + kt) * 64 + l) << 3];

    f32x4 acc[2];
    acc[0] = zero4; acc[1] = zero4;
#pragma unroll
    for (int ci = 0; ci < 2; ci++) {
        int ct = cp * 2 + ci;
#pragma unroll
        for (int kt = 0; kt < 4; kt++) {
            int slot = ((ct * 16 + m16) << 4) | ((((kt << 2) | kg)) ^ (m16 & 7));
            bf16x8 aV = *(const bf16x8*)&Vs[slot << 3];
            acc[ci] = __builtin_amdgcn_mfma_f32_16x16x32_bf16(aV, bE[kt], acc[ci], 0, 0, 0);
        }
    }
    f32x4 accS = zero4;
    if (cp == 0) {
        bf16x8 ones;
        short ov = (m16 == 0) ? (short)0x3F80 : (short)0;
#pragma unroll
        for (int j = 0; j < 8; j++) ones[j] = ov;
#pragma unroll
        for (int kt = 0; kt < 4; kt++)
            accS = __builtin_amdgcn_mfma_f32_16x16x32_bf16(ones, bE[kt], accS, 0, 0, 0);
    }

    // ---- epilogue: shfl-repack -> one us8 store per lane ----
    u32x2 pk[2];
#pragma unroll
    for (int ci = 0; ci < 2; ci++) {
        pk[ci].x = (unsigned)f2bf(acc[ci][0]) | ((unsigned)f2bf(acc[ci][1]) << 16);
        pk[ci].y = (unsigned)f2bf(acc[ci][2]) | ((unsigned)f2bf(acc[ci][3]) << 16);
    }
    int q = l & 3, hrow = l >> 2;
    int sA = ((q & 1) << 5) | hrow;       // src lane kg=2*(q&1), m16=hrow
    int sB = sA + 16;                     // kg+1
    unsigned a0 = __shfl(pk[0].x, sA, 64), a1 = __shfl(pk[0].y, sA, 64);
    unsigned a2 = __shfl(pk[1].x, sA, 64), a3 = __shfl(pk[1].y, sA, 64);
    unsigned b0 = __shfl(pk[0].x, sB, 64), b1 = __shfl(pk[0].y, sB, 64);
    unsigned b2 = __shfl(pk[1].x, sB, 64), b3 = __shfl(pk[1].y, sB, 64);
    int cisel = q >> 1;
    uint4 o;
    o.x = cisel ? a2 : a0;  o.y = cisel ? a3 : a1;
    o.z = cisel ? b2 : b0;  o.w = cisel ? b3 : b1;
    long oaddr = (((long)(b * 128 + w)) * 128 + h0 + hq * 16 + hrow) * 64
               + cp * 32 + q * 8;
    *(uint4*)&accHt[oaddr] = o;

    if (cp == 0 && kg == 0)
        sH[(b * 128 + w) * 128 + h0 + hq * 16 + m16] = accS[0];
}

// ---------------------------------------------------------------------------
// Kernel 4: row attention + fused finalize, w-split. Block (b, h, wh).
// ---------------------------------------------------------------------------
__global__ __launch_bounds__(512) void rowW_fin_kernel(
    const u16* __restrict__ qkTr, const u16* __restrict__ vb16,
    const u16* __restrict__ accHt, const float* __restrict__ sH,
    const float* __restrict__ x, const float* __restrict__ gamma,
    float* __restrict__ out)
{
    __shared__ u16 Qpk[65 * 8];
    __shared__ u16 Kpk[129 * 8];
    __shared__ u16 Epk[1024 * 8];   // 16 KB
    __shared__ u16 Vs[1024 * 8];    // 16 KB

    int t = threadIdx.x;
    int bid = blockIdx.x;
    int wg = ((bid & 7) << 9) | (bid >> 3);
    int b = wg >> 8, h = (wg >> 1) & 127, wh = wg & 1;
    int w0 = wh << 6;
    float gm = gamma[0];

    int wv = t >> 6, l = t & 63;
    int m16 = l & 15, kg = l >> 4;
    int cp = wv >> 2, hq = wv & 3;
    int wcol = hq * 16 + m16;          // w within half
    int wfull = w0 + wcol;

    // ---- hoisted finalize loads ----
    float sHreg = sH[((long)(b * 128 + wfull)) * 128 + h];
    uint4 hAw;
    {
        long hb = (((long)(b * 128 + w0 + (hq << 4) + (l >> 2))) * 128 + h) * 64
                + cp * 32 + ((l & 3) << 3);
        hAw = *(const uint4*)&accHt[hb];
    }
    long obase = ((long)b << 20) + (h << 7) + wfull;
    float xr[2][4];
#pragma unroll
    for (int ci = 0; ci < 2; ci++)
#pragma unroll
        for (int r = 0; r < 4; r++)
            xr[ci][r] = x[obase + ((long)(cp * 32 + ci * 16 + (kg << 2) + r) << 14)];

    // ---- staging ----
    if (t < 64) {
        const u16* p = qkTr + (((long)((b << 14) + h * 128 + w0 + t)) << 4);
        *(us8*)&Qpk[t * 8] = *(const us8*)p;
    } else if (t == 64) {
        us8 z = {0,0,0,0,0,0,0,0};
        *(us8*)&Qpk[64 * 8] = z;
    } else if (t >= 128 && t < 256) {
        const u16* p = qkTr + (((long)((b << 14) + h * 128 + (t - 128))) << 4);
        *(us8*)&Kpk[(t - 128) * 8] = *(const us8*)(p + 8);
    } else if (t == 256) {
        us8 z = {0,0,0,0,0,0,0,0};
        *(us8*)&Kpk[128 * 8] = z;
    }

    const u16* vB = vb16 + ((long)b << 20) + (h << 7);
#pragma unroll
    for (int m = t; m < 1024; m += 512) {
        int c = m >> 4, s = m & 15;
        int src = (s & 8) | ((s ^ c) & 7);
        *(us8*)&Vs[m << 3] = *(const us8*)&vB[((long)c << 14) + (src << 3)];
    }

    // keep-alive pins (rule #17)
    {
        asm volatile("" :: "v"(sHreg), "v"(hAw.x), "v"(hAw.y), "v"(hAw.z), "v"(hAw.w));
        asm volatile("" :: "v"(xr[0][0]), "v"(xr[0][1]), "v"(xr[0][2]), "v"(xr[0][3]),
                          "v"(xr[1][0]), "v"(xr[1][1]), "v"(xr[1][2]), "v"(xr[1][3]));
    }
    __syncthreads();

    f32x4 zero4 = {0.f, 0.f, 0.f, 0.f};

    // ---- QK^T: wave owns v-tile gt=wv; E[v][w0+ht*16+m16], 4 ht, no mask ----
    int gt = wv;
    bf16x8 afr;
    { int sl = (kg == 0) ? (gt * 16 + m16) : 128;
      afr = *(const bf16x8*)&Kpk[sl * 8]; }
    int kgr = ((gt & 1) << 1) | (kg >> 1);
    int jb  = (kg & 1) << 2;
#pragma unroll
    for (int ht = 0; ht < 4; ht++) {
        int slB = (kg == 0) ? (ht * 16 + m16) : 64;
        bf16x8 bfr = *(const bf16x8*)&Qpk[slB * 8];
        f32x4 e = __builtin_amdgcn_mfma_f32_16x16x32_bf16(afr, bfr, zero4, 0, 0, 0);
        u16 u0[4];
#pragma unroll
        for (int r = 0; r < 4; r++) u0[r] = f2bf(__expf(e[r]));
        int eidx = ((((ht << 2) | (gt >> 1)) * 64 + kgr * 16 + m16) << 3) + jb;
        u32x2 pk2;
        pk2.x = (unsigned)u0[0] | ((unsigned)u0[1] << 16);
        pk2.y = (unsigned)u0[2] | ((unsigned)u0[3] << 16);
        *(u32x2*)&Epk[eidx] = pk2;
    }
    __syncthreads();

    // ---- PV: wave (cp, hq): c-tiles {2cp,2cp+1}, w-tile hq ----
    bf16x8 bE[4];
#pragma unroll
    for (int kt = 0; kt < 4; kt++)
        bE[kt] = *(const bf16x8*)&Epk[(((hq << 2) + kt) * 64 + l) << 3];

    f32x4 acc[2];
    acc[0] = zero4; acc[1] = zero4;
#pragma unroll
    for (int ci = 0; ci < 2; ci++) {
        int ct = cp * 2 + ci;
#pragma unroll
        for (int kt = 0; kt < 4; kt++) {
            int slot = ((ct * 16 + m16) << 4) | ((((kt << 2) | kg)) ^ (m16 & 7));
            bf16x8 aV = *(const bf16x8*)&Vs[slot << 3];
            acc[ci] = __builtin_amdgcn_mfma_f32_16x16x32_bf16(aV, bE[kt], acc[ci], 0, 0, 0);
        }
    }
    // ones row duplicated on BOTH cp halves so the sW shfl stays wave-local
    f32x4 accS = zero4;
    {
        bf16x8 ones;
        short ov = (m16 == 0) ? (short)0x3F80 : (short)0;
#pragma unroll
        for (int j = 0; j < 8; j++) ones[j] = ov;
#pragma unroll
        for (int kt = 0; kt < 4; kt++)
            accS = __builtin_amdgcn_mfma_f32_16x16x32_bf16(ones, bE[kt], accS, 0, 0, 0);
    }

    float sWv_ = __shfl(accS[0], m16, 64); // D[0][m16] lives in lane m16 (kg=0)
    float grv = gm / (sHreg + sWv_);

    // ---- redistribute accHt to (m16,kg) layout via shfls ----
    us4 hA[2];
#pragma unroll
    for (int ci = 0; ci < 2; ci++) {
        int s = (m16 << 2) | ((ci << 1) | (kg >> 1));
        unsigned t0 = __shfl(hAw.x, s, 64), t1 = __shfl(hAw.y, s, 64);
        unsigned t2 = __shfl(hAw.z, s, 64), t3 = __shfl(hAw.w, s, 64);
        unsigned wA = (kg & 1) ? t2 : t0;
        unsigned wB = (kg & 1) ? t3 : t1;
        uint2 uu2;
        uu2.x = wA; uu2.y = wB;
        hA[ci] = *(us4*)&uu2;
    }

    // ---- direct-from-register epilogue: out = grv*(accW+accH) + x ----
#pragma unroll
    for (int ci = 0; ci < 2; ci++) {
#pragma unroll
        for (int r = 0; r < 4; r++) {
            long ga = obase + ((long)(cp * 32 + ci * 16 + (kg << 2) + r) << 14);
            out[ga] = grv * (acc[ci][r] + bf2f(hA[ci][r])) + xr[ci][r];
        }
    }
}

extern "C" void kernel_launch(void* const* d_in, const int* in_sizes, int n_in,
                              void* d_out, int out_size, void* d_ws, size_t ws_size,
                              hipStream_t stream) {
    const float* x     = (const float*)d_in[0];
    const float* Wq    = (const float*)d_in[1];
    const float* bq    = (const float*)d_in[2];
    const float* Wk    = (const float*)d_in[3];
    const float* bk    = (const float*)d_in[4];
    const float* Wv    = (const float*)d_in[5];
    const float* bv    = (const float*)d_in[6];
    const float* gamma = (const float*)d_in[7];
    float* out = (float*)d_out;

    u16* vb16  = (u16*)d_ws;                 // 16,777,216 u16 (32MB)
    u16* vTc2  = vb16 + 16777216;            // 16,777,216 u16 (32MB) [b][oct][w][c][g8]
    u16* qkTr  = vTc2 + 16777216;            // 4,194,304 u16 (8MB)
    u16* accHt = qkTr + 4194304;             // 16,777,216 u16 (32MB)
    float* sH  = (float*)(accHt + 16777216); // 262,144 f32 (1MB)
    u16* Wpk   = (u16*)(sH + 262144);        // 5,120 u16
    float* biasf = (float*)(Wpk + 5120);     // 80 f32

    wprep_kernel<<<1, 256, 0, stream>>>(Wq, bq, Wk, bk, Wv, bv, Wpk, biasf);
    proj_kernel<<<1024, 256, 0, stream>>>(x, Wpk, biasf, vb16, vTc2, qkTr);
    colH_kernel<<<4096, 512, 0, stream>>>(qkTr, vTc2, accHt, sH);
    rowW_fin_kernel<<<4096, 512, 0, stream>>>(qkTr, vb16, accHt, sH, x, gamma, out);
}

// Round 14
// 86.616 us; speedup vs baseline: 1.3416x; 1.0983x over previous
//
#include <hip/hip_runtime.h>
#include <hip/hip_bf16.h>

// B=16, C=64, CQ=8, H=W=128
typedef unsigned short u16;
typedef unsigned int u32;
typedef __attribute__((ext_vector_type(8))) short    bf16x8;
typedef __attribute__((ext_vector_type(8))) unsigned short us8;
typedef __attribute__((ext_vector_type(4))) unsigned short us4;
typedef __attribute__((ext_vector_type(4))) float    f32x4;
typedef __attribute__((ext_vector_type(2))) unsigned int u32x2;

__device__ __forceinline__ u16 f2bf(float f) {
    unsigned u = __float_as_uint(f);
    return (u16)((u + 0x7FFFu + ((u >> 16) & 1u)) >> 16);
}
__device__ __forceinline__ float bf2f(u16 v) {
    return __uint_as_float((unsigned)v << 16);
}

// ---------------------------------------------------------------------------
// Kernel 0: W prep. Wpk[nt(5)][kt(2)][lane(64)][8]; biasf[80] = {bv,bq,bk}.
// ---------------------------------------------------------------------------
__global__ __launch_bounds__(256) void wprep_kernel(
    const float* __restrict__ Wq, const float* __restrict__ bq,
    const float* __restrict__ Wk, const float* __restrict__ bk,
    const float* __restrict__ Wv, const float* __restrict__ bv,
    u16* __restrict__ Wpk, float* __restrict__ biasf)
{
    int t = threadIdx.x;
    for (int s = t; s < 640; s += 256) {
        int nt = s >> 7;
        int kt = (s >> 6) & 1;
        int l  = s & 63;
        int n  = (nt << 4) | (l & 15);
        int k0 = kt * 32 + ((l >> 4) << 3);
        const float* row;
        if (n < 64) row = Wv + n * 64;
        else if (n < 72) row = Wq + (n - 64) * 64;
        else row = Wk + (n - 72) * 64;
        us8 o;
#pragma unroll
        for (int j = 0; j < 8; j++) o[j] = f2bf(row[k0 + j]);
        *(us8*)&Wpk[s * 8] = o;
    }
    if (t < 80) {
        float bb;
        if (t < 64) bb = bv[t];
        else if (t < 72) bb = bq[t - 64];
        else bb = bk[t - 72];
        biasf[t] = bb;
    }
}

// ---------------------------------------------------------------------------
// Kernel 1: projections via MFMA. 8h x 16w tile, 2048 blocks x 256 thr.
// Outputs ONLY vTc2[b][oct][w][c][g8] and qkTr[b][h][w][16]. No vb16.
// ---------------------------------------------------------------------------
__global__ __launch_bounds__(256) void proj_kernel(
    const float* __restrict__ x, const u16* __restrict__ Wpk,
    const float* __restrict__ biasf,
    u16* __restrict__ vTc2, u16* __restrict__ qkTr)
{
    __shared__ u16 vstage[16 * 65 * 8];   // 16.25 KB: [w16][c64+1pad][g8]
    __shared__ u16 qstage[4][32 * 16];    // 4 KB

    int t = threadIdx.x;
    int bid = blockIdx.x;
    int wg = ((bid & 7) << 8) | (bid >> 3);   // bijective (2048 = 8*256)
    int b = wg >> 7;
    int hg = (wg >> 3) & 15;                  // h-oct 0..15
    int wq = wg & 7;
    int h0 = hg << 3, w0 = wq << 4;
    const float* xb = x + ((long)b << 20);

    int wv = t >> 6, l = t & 63;
    int m16 = l & 15, kg = l >> 4;

    // ---- A-frags direct from global: m-tile mt -> h-row h0+wv*2+mt ----
    bf16x8 af[2][2];
#pragma unroll
    for (int mt = 0; mt < 2; mt++) {
        int base = ((h0 + wv * 2 + mt) << 7) + w0 + m16;
#pragma unroll
        for (int kt = 0; kt < 2; kt++) {
            float v[8];
#pragma unroll
            for (int j = 0; j < 8; j++)
                v[j] = xb[((kt * 32 + (kg << 3) + j) << 14) + base];
            us8 a;
#pragma unroll
            for (int j = 0; j < 8; j++) a[j] = f2bf(v[j]);
            af[mt][kt] = (bf16x8)a;
        }
    }

    f32x4 acc[2][5];
#pragma unroll
    for (int nt = 0; nt < 5; nt++) {
        float bb = biasf[(nt << 4) + m16];
        f32x4 binit = {bb, bb, bb, bb};
        bf16x8 b0 = *(const bf16x8*)&Wpk[(((nt << 1) + 0) << 9) + (l << 3)];
        bf16x8 b1 = *(const bf16x8*)&Wpk[(((nt << 1) + 1) << 9) + (l << 3)];
#pragma unroll
        for (int mt = 0; mt < 2; mt++) {
            f32x4 a_ = binit;
            a_ = __builtin_amdgcn_mfma_f32_16x16x32_bf16(af[mt][0], b0, a_, 0, 0, 0);
            a_ = __builtin_amdgcn_mfma_f32_16x16x32_bf16(af[mt][1], b1, a_, 0, 0, 0);
            acc[mt][nt] = a_;
        }
    }

    // ---- vstage: u32 = {g=wv*2 (mt0), g=wv*2+1 (mt1)} at [wl][c] ----
#pragma unroll
    for (int nt = 0; nt < 4; nt++) {
#pragma unroll
        for (int r = 0; r < 4; r++) {
            int c = (nt << 4) + m16;
            int wl = (kg << 2) + r;        // D row m = kg*4+r -> w offset
            u32 pkv = (u32)f2bf(acc[0][nt][r]) | ((u32)f2bf(acc[1][nt][r]) << 16);
            *(u32*)((char*)vstage + wl * 1040 + c * 16 + wv * 4) = pkv;
        }
    }

    // ---- qk: wave-local LDS transpose -> 2x512B coalesced stores ----
    {
        u16* qs = qstage[wv];
#pragma unroll
        for (int mt = 0; mt < 2; mt++) {
#pragma unroll
            for (int r = 0; r < 4; r++)
                qs[((mt << 4) + (kg << 2) + r) * 16 + m16] = f2bf(acc[mt][4][r]);
        }
        int pixl = l >> 1, half = l & 1;
        us8 o = *(us8*)&qs[pixl * 16 + half * 8];
        int hgl = h0 + wv * 2 + (pixl >> 4);
        int wgl = w0 + (pixl & 15);
        *(us8*)&qkTr[(((long)((b << 14) + hgl * 128 + wgl)) << 4) + half * 8] = o;
    }
    __syncthreads();

    // ---- vTc2 write-out: 4 iters, 1KB contiguous per wave-instr ----
#pragma unroll
    for (int u = 0; u < 4; u++) {
        int lin = (u << 8) + t;           // [wl][c]
        int c = lin & 63, wl = lin >> 6;
        us8 vv = *(const us8*)((char*)vstage + wl * 1040 + c * 16);
        long dst = ((((long)(b * 16 + hg)) * 128 + w0 + wl) * 64 + c) << 3;
        *(us8*)&vTc2[dst] = vv;
    }
}

// ---------------------------------------------------------------------------
// Kernel 3: column attention, h-split. Block (b, w, hh); 4096 blocks.
// ---------------------------------------------------------------------------
__global__ __launch_bounds__(512) void colH_kernel(
    const u16* __restrict__ qkTr, const u16* __restrict__ vTc2,
    u16* __restrict__ accHt, float* __restrict__ sH)
{
    __shared__ u16 Qpk[65 * 8];
    __shared__ u16 Kpk[129 * 8];
    __shared__ u16 Epk[1024 * 8];      // 16 KB
    __shared__ u16 Vs[1024 * 8];       // 16 KB

    int t = threadIdx.x;
    int bid = blockIdx.x;
    int wg = ((bid & 7) << 9) | (bid >> 3);
    int b = wg >> 8, w = (wg >> 1) & 127, hh = wg & 1;
    int h0 = hh << 6;

    if (t < 64) {
        const u16* p = qkTr + (((long)((b << 14) + (h0 + t) * 128 + w)) << 4);
        *(us8*)&Qpk[t * 8] = *(const us8*)p;
    } else if (t == 64) {
        us8 z = {0,0,0,0,0,0,0,0};
        *(us8*)&Qpk[64 * 8] = z;
    } else if (t >= 128 && t < 256) {
        const u16* p = qkTr + (((long)((b << 14) + (t - 128) * 128 + w)) << 4);
        *(us8*)&Kpk[(t - 128) * 8] = *(const us8*)(p + 8);
    } else if (t == 256) {
        us8 z = {0,0,0,0,0,0,0,0};
        *(us8*)&Kpk[128 * 8] = z;
    }

#pragma unroll
    for (int m = t; m < 1024; m += 512) {
        int c = m >> 4, s = m & 15;
        int oct = (s & 8) | ((s ^ c) & 7);
        const u16* srcp = vTc2 + ((((long)(b * 16 + oct)) * 128 + w) * 64 + c) * 8;
        *(us8*)&Vs[m << 3] = *(const us8*)srcp;
    }
    __syncthreads();

    int wv = t >> 6, l = t & 63;
    int m16 = l & 15, kg = l >> 4;
    f32x4 zero4 = {0.f, 0.f, 0.f, 0.f};

    // ---- QK^T: wave owns g-tile gt=wv; E[g][h0+ht*16+m16], 4 ht ----
    int gt = wv;
    bf16x8 afr;
    { int sl = (kg == 0) ? (gt * 16 + m16) : 128;
      afr = *(const bf16x8*)&Kpk[sl * 8]; }
    int kgr = ((gt & 1) << 1) | (kg >> 1);
    int jb  = (kg & 1) << 2;
    int gbase = gt * 16 + kg * 4;
#pragma unroll
    for (int ht = 0; ht < 4; ht++) {
        int slB = (kg == 0) ? (ht * 16 + m16) : 64;
        bf16x8 bfr = *(const bf16x8*)&Qpk[slB * 8];
        f32x4 e = __builtin_amdgcn_mfma_f32_16x16x32_bf16(afr, bfr, zero4, 0, 0, 0);
        u16 u0[4];
#pragma unroll
        for (int r = 0; r < 4; r++) {
            int g = gbase + r, h = h0 + ht * 16 + m16;
            float val = (g == h) ? 0.f : __expf(e[r]);
            u0[r] = f2bf(val);
        }
        int eidx = ((((ht << 2) | (gt >> 1)) * 64 + kgr * 16 + m16) << 3) + jb;
        u32x2 pk2;
        pk2.x = (unsigned)u0[0] | ((unsigned)u0[1] << 16);
        pk2.y = (unsigned)u0[2] | ((unsigned)u0[3] << 16);
        *(u32x2*)&Epk[eidx] = pk2;
    }
    __syncthreads();

    // ---- PV: wave (cp, hq): c-tiles {2cp,2cp+1}, h-tile hq ----
    int cp = wv >> 2, hq = wv & 3;
    bf16x8 bE[4];
#pragma unroll
    for (int kt = 0; kt < 4; kt++)
        bE[kt] = *(const bf16x8*)&Epk[(((hq << 2) + kt) * 64 + l) << 3];

    f32x4 acc[2];
    acc[0] = zero4; acc[1] = zero4;
#pragma unroll
    for (int ci = 0; ci < 2; ci++) {
        int ct = cp * 2 + ci;
#pragma unroll
        for (int kt = 0; kt < 4; kt++) {
            int slot = ((ct * 16 + m16) << 4) | ((((kt << 2) | kg)) ^ (m16 & 7));
            bf16x8 aV = *(const bf16x8*)&Vs[slot << 3];
            acc[ci] = __builtin_amdgcn_mfma_f32_16x16x32_bf16(aV, bE[kt], acc[ci], 0, 0, 0);
        }
    }
    f32x4 accS = zero4;
    if (cp == 0) {
        bf16x8 ones;
        short ov = (m16 == 0) ? (short)0x3F80 : (short)0;
#pragma unroll
        for (int j = 0; j < 8; j++) ones[j] = ov;
#pragma unroll
        for (int kt = 0; kt < 4; kt++)
            accS = __builtin_amdgcn_mfma_f32_16x16x32_bf16(ones, bE[kt], accS, 0, 0, 0);
    }

    // ---- epilogue: shfl-repack -> one us8 store per lane ----
    u32x2 pk[2];
#pragma unroll
    for (int ci = 0; ci < 2; ci++) {
        pk[ci].x = (unsigned)f2bf(acc[ci][0]) | ((unsigned)f2bf(acc[ci][1]) << 16);
        pk[ci].y = (unsigned)f2bf(acc[ci][2]) | ((unsigned)f2bf(acc[ci][3]) << 16);
    }
    int q = l & 3, hrow = l >> 2;
    int sA = ((q & 1) << 5) | hrow;
    int sB = sA + 16;
    unsigned a0 = __shfl(pk[0].x, sA, 64), a1 = __shfl(pk[0].y, sA, 64);
    unsigned a2 = __shfl(pk[1].x, sA, 64), a3 = __shfl(pk[1].y, sA, 64);
    unsigned b0 = __shfl(pk[0].x, sB, 64), b1 = __shfl(pk[0].y, sB, 64);
    unsigned b2 = __shfl(pk[1].x, sB, 64), b3 = __shfl(pk[1].y, sB, 64);
    int cisel = q >> 1;
    uint4 o;
    o.x = cisel ? a2 : a0;  o.y = cisel ? a3 : a1;
    o.z = cisel ? b2 : b0;  o.w = cisel ? b3 : b1;
    long oaddr = (((long)(b * 128 + w)) * 128 + h0 + hq * 16 + hrow) * 64
               + cp * 32 + q * 8;
    *(uint4*)&accHt[oaddr] = o;

    if (cp == 0 && kg == 0)
        sH[(b * 128 + w) * 128 + h0 + hq * 16 + m16] = accS[0];
}

// ---------------------------------------------------------------------------
// Kernel 4: row attention + fused finalize + in-block V-compute.
// Block (b, h, wh). x row staged once (bf16 LDS, stride 130) serving both
// the V-GEMM (replacing the vb16 global read) and the residual.
// ---------------------------------------------------------------------------
__global__ __launch_bounds__(512) void rowW_fin_kernel(
    const u16* __restrict__ qkTr, const u16* __restrict__ Wpk,
    const float* __restrict__ biasf,
    const u16* __restrict__ accHt, const float* __restrict__ sH,
    const float* __restrict__ x, const float* __restrict__ gamma,
    float* __restrict__ out)
{
    __shared__ u16 Qpk[65 * 8];
    __shared__ u16 Kpk[129 * 8];
    __shared__ u16 Epk[1024 * 8];   // 16 KB
    __shared__ u16 Vs[1024 * 8];    // 16 KB
    __shared__ u16 xs[64 * 130];    // 16.25 KB: x row bf16, stride 130

    int t = threadIdx.x;
    int bid = blockIdx.x;
    int wg = ((bid & 7) << 9) | (bid >> 3);
    int b = wg >> 8, h = (wg >> 1) & 127, wh = wg & 1;
    int w0 = wh << 6;
    float gm = gamma[0];

    int wv = t >> 6, l = t & 63;
    int m16 = l & 15, kg = l >> 4;
    int cp = wv >> 2, hq = wv & 3;
    int wcol = hq * 16 + m16;
    int wfull = w0 + wcol;

    // ---- hoisted finalize loads ----
    float sHreg = sH[((long)(b * 128 + wfull)) * 128 + h];
    uint4 hAw;
    {
        long hb = (((long)(b * 128 + w0 + (hq << 4) + (l >> 2))) * 128 + h) * 64
                + cp * 32 + ((l & 3) << 3);
        hAw = *(const uint4*)&accHt[hb];
    }

    // ---- staging: Qpk/Kpk + full x row (coalesced f32 -> bf16) ----
    if (t < 64) {
        const u16* p = qkTr + (((long)((b << 14) + h * 128 + w0 + t)) << 4);
        *(us8*)&Qpk[t * 8] = *(const us8*)p;
    } else if (t == 64) {
        us8 z = {0,0,0,0,0,0,0,0};
        *(us8*)&Qpk[64 * 8] = z;
    } else if (t >= 128 && t < 256) {
        const u16* p = qkTr + (((long)((b << 14) + h * 128 + (t - 128))) << 4);
        *(us8*)&Kpk[(t - 128) * 8] = *(const us8*)(p + 8);
    } else if (t == 256) {
        us8 z = {0,0,0,0,0,0,0,0};
        *(us8*)&Kpk[128 * 8] = z;
    }

    const float* xrow = x + ((long)b << 20) + (h << 7);
#pragma unroll
    for (int it = 0; it < 4; it++) {
        int base = it * 2048 + t * 4;       // element in [c][w] row-major
        int c = base >> 7, w_ = base & 127;
        float4 xv = *(const float4*)&xrow[((long)c << 14) + w_];
        u32 lo = (u32)f2bf(xv.x) | ((u32)f2bf(xv.y) << 16);
        u32 hi = (u32)f2bf(xv.z) | ((u32)f2bf(xv.w) << 16);
        u32* dst = (u32*)&xs[c * 130 + w_];
        dst[0] = lo; dst[1] = hi;
    }

    // keep-alive pins (rule #17)
    asm volatile("" :: "v"(sHreg), "v"(hAw.x), "v"(hAw.y), "v"(hAw.z), "v"(hAw.w));
    __syncthreads();

    f32x4 zero4 = {0.f, 0.f, 0.f, 0.f};

    // ---- V-GEMM: V[c][v] = Wv x + bv; wave wv owns v-tile (16 v) ----
    {
        bf16x8 xa[2];
#pragma unroll
        for (int kt = 0; kt < 2; kt++) {
            us8 a;
#pragma unroll
            for (int j = 0; j < 8; j++)
                a[j] = xs[(kt * 32 + (kg << 3) + j) * 130 + (wv << 4) + m16];
            xa[kt] = (bf16x8)a;
        }
#pragma unroll
        for (int nt = 0; nt < 4; nt++) {
            float bb = biasf[(nt << 4) + m16];
            f32x4 a_ = {bb, bb, bb, bb};
            bf16x8 b0 = *(const bf16x8*)&Wpk[(((nt << 1) + 0) << 9) + (l << 3)];
            bf16x8 b1 = *(const bf16x8*)&Wpk[(((nt << 1) + 1) << 9) + (l << 3)];
            a_ = __builtin_amdgcn_mfma_f32_16x16x32_bf16(xa[0], b0, a_, 0, 0, 0);
            a_ = __builtin_amdgcn_mfma_f32_16x16x32_bf16(xa[1], b1, a_, 0, 0, 0);
            int c = (nt << 4) + m16;
            int oo = (wv << 1) + (kg >> 1);          // v-oct 0..15
            int s = (oo & 8) | ((oo ^ c) & 7);
            us4 pkd = { f2bf(a_[0]), f2bf(a_[1]), f2bf(a_[2]), f2bf(a_[3]) };
            *(us4*)&Vs[(((c << 4) | s) << 3) + ((kg & 1) << 2)] = pkd;
        }
    }

    // ---- QK^T: wave owns v-tile gt=wv; E[v][w0+ht*16+m16], no mask ----
    int gt = wv;
    bf16x8 afr;
    { int sl = (kg == 0) ? (gt * 16 + m16) : 128;
      afr = *(const bf16x8*)&Kpk[sl * 8]; }
    int kgr = ((gt & 1) << 1) | (kg >> 1);
    int jb  = (kg & 1) << 2;
#pragma unroll
    for (int ht = 0; ht < 4; ht++) {
        int slB = (kg == 0) ? (ht * 16 + m16) : 64;
        bf16x8 bfr = *(const bf16x8*)&Qpk[slB * 8];
        f32x4 e = __builtin_amdgcn_mfma_f32_16x16x32_bf16(afr, bfr, zero4, 0, 0, 0);
        u16 u0[4];
#pragma unroll
        for (int r = 0; r < 4; r++) u0[r] = f2bf(__expf(e[r]));
        int eidx = ((((ht << 2) | (gt >> 1)) * 64 + kgr * 16 + m16) << 3) + jb;
        u32x2 pk2;
        pk2.x = (unsigned)u0[0] | ((unsigned)u0[1] << 16);
        pk2.y = (unsigned)u0[2] | ((unsigned)u0[3] << 16);
        *(u32x2*)&Epk[eidx] = pk2;
    }
    __syncthreads();

    // ---- PV: wave (cp, hq): c-tiles {2cp,2cp+1}, w-tile hq ----
    bf16x8 bE[4];
#pragma unroll
    for (int kt = 0; kt < 4; kt++)
        bE[kt] = *(const bf16x8*)&Epk[(((hq << 2) + kt) * 64 + l) << 3];

    f32x4 acc[2];
    acc[0] = zero4; acc[1] = zero4;
#pragma unroll
    for (int ci = 0; ci < 2; ci++) {
        int ct = cp * 2 + ci;
#pragma unroll
        for (int kt = 0; kt < 4; kt++) {
            int slot = ((ct * 16 + m16) << 4) | ((((kt << 2) | kg)) ^ (m16 & 7));
            bf16x8 aV = *(const bf16x8*)&Vs[slot << 3];
            acc[ci] = __builtin_amdgcn_mfma_f32_16x16x32_bf16(aV, bE[kt], acc[ci], 0, 0, 0);
        }
    }
    f32x4 accS = zero4;
    {
        bf16x8 ones;
        short ov = (m16 == 0) ? (short)0x3F80 : (short)0;
#pragma unroll
        for (int j = 0; j < 8; j++) ones[j] = ov;
#pragma unroll
        for (int kt = 0; kt < 4; kt++)
            accS = __builtin_amdgcn_mfma_f32_16x16x32_bf16(ones, bE[kt], accS, 0, 0, 0);
    }

    float sWv_ = __shfl(accS[0], m16, 64);
    float grv = gm / (sHreg + sWv_);

    // ---- redistribute accHt to (m16,kg) layout via shfls ----
    us4 hA[2];
#pragma unroll
    for (int ci = 0; ci < 2; ci++) {
        int s = (m16 << 2) | ((ci << 1) | (kg >> 1));
        unsigned t0 = __shfl(hAw.x, s, 64), t1 = __shfl(hAw.y, s, 64);
        unsigned t2 = __shfl(hAw.z, s, 64), t3 = __shfl(hAw.w, s, 64);
        unsigned wA = (kg & 1) ? t2 : t0;
        unsigned wB = (kg & 1) ? t3 : t1;
        uint2 uu2;
        uu2.x = wA; uu2.y = wB;
        hA[ci] = *(us4*)&uu2;
    }

    // ---- epilogue: out = grv*(accW+accH) + x (x residual from xs) ----
    long obase = ((long)b << 20) + (h << 7) + wfull;
#pragma unroll
    for (int ci = 0; ci < 2; ci++) {
#pragma unroll
        for (int r = 0; r < 4; r++) {
            int c = cp * 32 + ci * 16 + (kg << 2) + r;
            float xv = bf2f(xs[c * 130 + wfull]);
            long ga = obase + ((long)c << 14);
            out[ga] = grv * (acc[ci][r] + bf2f(hA[ci][r])) + xv;
        }
    }
}

extern "C" void kernel_launch(void* const* d_in, const int* in_sizes, int n_in,
                              void* d_out, int out_size, void* d_ws, size_t ws_size,
                              hipStream_t stream) {
    const float* x     = (const float*)d_in[0];
    const float* Wq    = (const float*)d_in[1];
    const float* bq    = (const float*)d_in[2];
    const float* Wk    = (const float*)d_in[3];
    const float* bk    = (const float*)d_in[4];
    const float* Wv    = (const float*)d_in[5];
    const float* bv    = (const float*)d_in[6];
    const float* gamma = (const float*)d_in[7];
    float* out = (float*)d_out;

    u16* vTc2  = (u16*)d_ws;                 // 16,777,216 u16 (32MB) [b][oct][w][c][g8]
    u16* qkTr  = vTc2 + 16777216;            // 4,194,304 u16 (8MB)
    u16* accHt = qkTr + 4194304;             // 16,777,216 u16 (32MB)
    float* sH  = (float*)(accHt + 16777216); // 262,144 f32 (1MB)
    u16* Wpk   = (u16*)(sH + 262144);        // 5,120 u16
    float* biasf = (float*)(Wpk + 5120);     // 80 f32

    wprep_kernel<<<1, 256, 0, stream>>>(Wq, bq, Wk, bk, Wv, bv, Wpk, biasf);
    proj_kernel<<<2048, 256, 0, stream>>>(x, Wpk, biasf, vTc2, qkTr);
    colH_kernel<<<4096, 512, 0, stream>>>(qkTr, vTc2, accHt, sH);
    rowW_fin_kernel<<<4096, 512, 0, stream>>>(qkTr, Wpk, biasf, accHt, sH, x, gamma, out);
}